// Round 5
// baseline (1899.032 us; speedup 1.0000x reference)
//
#include <hip/hip_runtime.h>

// HeteroGraphSAGE on MI355X — fp32 I/O, bf16 MFMA internals.
// R5: (1) partitioned bucket build — LDS counters, per-block private bucket
//     slices (kills 2M global atomics + 119MB scattered write-allocate traffic);
//     (2) bf16 shadow copies of gather sources (x_card, x_merch, h_c) when
//     ws_size permits -> all gathers read bf16 (~40% less gather traffic).
//
// ws layout (bytes):
//   cnt_m    @ 0        (50000*4)
//   cnt_c    @ 256K     (100000*4)
//   bucket_m @ 1  MiB   (50000*64*4  u32 card ids)
//   bucket_c @ 14 MiB   (100000*64*2 u16 merchant ids)
//   h_m      @ 27 MiB   (50000*128*2 bf16)
//   packed   @ 40 MiB   (10 * 32 KiB bf16)
//   -- shadow region (only if ws_size >= 87 MiB) --
//   xc_bf    @ 41 MiB   (100000*64*2  = 12.8 MB)
//   xm_bf    @ 54 MiB   (50000*64*2   = 6.4 MB)
//   hc_bf    @ 61 MiB   (100000*128*2 = 25.6 MB)

typedef unsigned short u16;
typedef unsigned int u32;
typedef short bf16x8 __attribute__((ext_vector_type(8)));
typedef float f32x4 __attribute__((ext_vector_type(4)));
typedef u16 u16x4 __attribute__((ext_vector_type(4)));
typedef u16 u16x8 __attribute__((ext_vector_type(8)));

#define CAP 64
#define LDS_PAD 8
#define NPART 32   // partitions per edge direction in bucket build

__device__ __forceinline__ float bf2f(u16 u) {
    union { u32 i; float f; } v; v.i = ((u32)u) << 16; return v.f;
}
__device__ __forceinline__ u16 f2bf(float f) {
    union { float f; u32 i; } v; v.f = f;
    u32 i = v.i;
    return (u16)((i + 0x7FFFu + ((i >> 16) & 1u)) >> 16);   // RNE
}
__device__ __forceinline__ bf16x8 cvt8(const float* p) {
    bf16x8 r;
#pragma unroll
    for (int i = 0; i < 8; ++i) r[i] = (short)f2bf(p[i]);
    return r;
}

// ---------------- weight packing: fp32 W[K,Nsrc] -> bf16 MFMA B fragments ----------------
struct PackDesc { const float* src; u16* dst; int K; int Nsrc; int ntOff; };
struct PackArgs { PackDesc d[12]; };

__global__ void __launch_bounds__(256) pack_all(PackArgs pa) {
    PackDesc pd = pa.d[blockIdx.y];
    int idx = blockIdx.x * 256 + threadIdx.x;          // < 16384
    int j = idx & 7;
    int lane = (idx >> 3) & 63;
    int t = idx >> 9;
    int nLocal = pd.Nsrc >> 4;
    int ntl = t % nLocal;
    int kt = t / nLocal;
    if (kt >= (pd.K >> 5)) return;
    int k = kt * 32 + ((lane >> 4) << 3) + j;
    int n = ntl * 16 + (lane & 15);
    pd.dst[(((kt * 8 + pd.ntOff + ntl) * 64) + lane) * 8 + j] = f2bf(pd.src[k * pd.Nsrc + n]);
}

// ---------------- fp32 -> bf16 shadow conversion ----------------
__global__ void __launch_bounds__(256) f32_to_bf16(
    const float* __restrict__ a, u16* __restrict__ b, int n)   // n % 4 == 0
{
    int i = (blockIdx.x * 256 + threadIdx.x) * 4;
    if (i >= n) return;
    f32x4 v = *reinterpret_cast<const f32x4*>(a + i);
    u16x4 o;
#pragma unroll
    for (int j = 0; j < 4; ++j) o[j] = f2bf(v[j]);
    *reinterpret_cast<u16x4*>(b + i) = o;
}

// ---------------- partitioned bucket build ----------------
// grid = 2*NPART blocks. Block owns a contiguous dst range; counters in LDS;
// bucket slice is block-private -> single-writer cache lines.
__global__ void __launch_bounds__(256) build_buckets_part(
    const int* __restrict__ src_cm, const int* __restrict__ dst_cm,
    const int* __restrict__ src_mc, const int* __restrict__ dst_mc,
    int* __restrict__ cnt_m, u32* __restrict__ bucket_m,
    int* __restrict__ cnt_c, u16* __restrict__ bucket_c,
    int E, int nMerch, int nCard)
{
    __shared__ int lcnt[3136];   // >= ceil(100000/NPART) = 3125
    const bool dirA = blockIdx.x < NPART;           // A: dst_cm -> merchants
    const int part = dirA ? blockIdx.x : blockIdx.x - NPART;
    const int nNode = dirA ? nMerch : nCard;
    const int lo = (int)((long long)part * nNode / NPART);
    const int hi = (int)((long long)(part + 1) * nNode / NPART);
    const int nLoc = hi - lo;
    const int* dst = dirA ? dst_cm : dst_mc;
    const int* src = dirA ? src_cm : src_mc;

    for (int i = threadIdx.x; i < nLoc; i += 256) lcnt[i] = 0;
    __syncthreads();

    for (int base = threadIdx.x * 4; base < E; base += 1024) {
        if (base + 4 <= E) {
            int4 d4 = *reinterpret_cast<const int4*>(dst + base);
            int dv[4] = {d4.x, d4.y, d4.z, d4.w};
#pragma unroll
            for (int j = 0; j < 4; ++j) {
                int d = dv[j];
                if (d >= lo && d < hi) {
                    int slot = atomicAdd(&lcnt[d - lo], 1);
                    if (slot < CAP) {
                        int s = src[base + j];
                        if (dirA) bucket_m[(size_t)d * CAP + slot] = (u32)s;
                        else      bucket_c[(size_t)d * CAP + slot] = (u16)s;
                    }
                }
            }
        } else {
            for (int i = base; i < E; ++i) {
                int d = dst[i];
                if (d >= lo && d < hi) {
                    int slot = atomicAdd(&lcnt[d - lo], 1);
                    if (slot < CAP) {
                        int s = src[i];
                        if (dirA) bucket_m[(size_t)d * CAP + slot] = (u32)s;
                        else      bucket_c[(size_t)d * CAP + slot] = (u16)s;
                    }
                }
            }
        }
    }
    __syncthreads();
    int* gcnt = dirA ? cnt_m : cnt_c;
    for (int i = threadIdx.x; i < nLoc; i += 256) gcnt[lo + i] = lcnt[i];
}

// ---------------- fused SAGE layer ----------------
// out[M,128] = relu(mean_nbr(Xsrc) @ Wl + Xdst @ Wr + bias)
// Gather: 4 neighbor-groups x 16 feature-lanes x 2 banks (8 nbrs/step).
// SRCF/DSTF: fp32 (true) or bf16 (false). OUTF: fp32 out. SHADOW: also write bf16 copy.
template<typename IdxT, int KF, bool SRCF, bool DSTF, bool OUTF, bool SHADOW>
__global__ void __launch_bounds__(256) sage_fused(
    const void* __restrict__ Xsrc_, const IdxT* __restrict__ adj,
    const int* __restrict__ cnt,
    const u16* __restrict__ Wlp, const void* __restrict__ Xdst_,
    const u16* __restrict__ Wrp, const float* __restrict__ bias,
    void* __restrict__ out_, u16* __restrict__ out_bf, int M)
{
    constexpr int NV = KF / 16;         // values per lane per neighbor
    __shared__ alignas(16) u16 lds[4][16][128 + LDS_PAD];
    const int lane = threadIdx.x & 63;
    const int wv = threadIdx.x >> 6;
    const int m0 = (blockIdx.x * 4 + wv) * 16;
    const bool active = (m0 < M);
    const int quad = lane >> 4;
    const int l15 = lane & 15;
    const int nb = quad;
    const int fl = l15;

    if (active) {
        const float* srcF = (const float*)Xsrc_;
        const u16*   srcH = (const u16*)Xsrc_;
        for (int r = 0; r < 16; ++r) {
            int node = m0 + r;
            int c = cnt[node];
            int cc = min(c, CAP);
            int sidx = (lane < cc) ? (int)adj[(size_t)node * CAP + lane] : 0;
            float inv = 1.f / (float)max(c, 1);
            float acc0[NV], acc1[NV];
#pragma unroll
            for (int i = 0; i < NV; ++i) { acc0[i] = 0.f; acc1[i] = 0.f; }
            for (int t = 0; t < cc; t += 8) {
                int k0 = t + nb;
                int k1 = t + nb + 4;
                int s0 = __shfl(sidx, k0);
                int s1 = __shfl(sidx, k1);
                bool p0 = k0 < cc;
                bool p1 = k1 < cc;
                if constexpr (SRCF) {
                    const f32x4* q0 = (const f32x4*)(srcF + (size_t)s0 * KF + fl * NV);
                    const f32x4* q1 = (const f32x4*)(srcF + (size_t)s1 * KF + fl * NV);
                    f32x4 u0 = q0[0];
                    f32x4 u1 = q1[0];
                    if constexpr (NV == 8) {
                        f32x4 w0 = q0[1];
                        f32x4 w1 = q1[1];
#pragma unroll
                        for (int i = 0; i < 4; ++i) {
                            acc0[4 + i] += p0 ? w0[i] : 0.f;
                            acc1[4 + i] += p1 ? w1[i] : 0.f;
                        }
                    }
#pragma unroll
                    for (int i = 0; i < 4; ++i) {
                        acc0[i] += p0 ? u0[i] : 0.f;
                        acc1[i] += p1 ? u1[i] : 0.f;
                    }
                } else {
                    if constexpr (NV == 8) {
                        bf16x8 u0 = *(const bf16x8*)(srcH + (size_t)s0 * KF + fl * 8);
                        bf16x8 u1 = *(const bf16x8*)(srcH + (size_t)s1 * KF + fl * 8);
#pragma unroll
                        for (int i = 0; i < 8; ++i) {
                            acc0[i] += p0 ? bf2f((u16)u0[i]) : 0.f;
                            acc1[i] += p1 ? bf2f((u16)u1[i]) : 0.f;
                        }
                    } else {
                        u16x4 u0 = *(const u16x4*)(srcH + (size_t)s0 * KF + fl * 4);
                        u16x4 u1 = *(const u16x4*)(srcH + (size_t)s1 * KF + fl * 4);
#pragma unroll
                        for (int i = 0; i < 4; ++i) {
                            acc0[i] += p0 ? bf2f(u0[i]) : 0.f;
                            acc1[i] += p1 ? bf2f(u1[i]) : 0.f;
                        }
                    }
                }
            }
            u16 packed[NV];
#pragma unroll
            for (int i = 0; i < NV; ++i) {
                float m = acc0[i] + acc1[i];
                m += __shfl_xor(m, 16);
                m += __shfl_xor(m, 32);
                packed[i] = f2bf(m * inv);
            }
            if (nb == 0) {
                if constexpr (NV == 8) *(u16x8*)&lds[wv][r][fl * 8] = *(const u16x8*)packed;
                else                   *(u16x4*)&lds[wv][r][fl * 4] = *(const u16x4*)packed;
            }
        }
    }
    __syncthreads();
    if (!active) return;

    constexpr int KT = KF >> 5;
    f32x4 acc[8];
#pragma unroll
    for (int i = 0; i < 8; ++i) acc[i] = (f32x4){0.f, 0.f, 0.f, 0.f};

#pragma unroll
    for (int kt = 0; kt < KT; ++kt) {
        bf16x8 a = *reinterpret_cast<const bf16x8*>(&lds[wv][l15][kt * 32 + quad * 8]);
#pragma unroll
        for (int nt = 0; nt < 8; ++nt) {
            bf16x8 b = *reinterpret_cast<const bf16x8*>(Wlp + (size_t)(((kt * 8 + nt) * 64 + lane) * 8));
            acc[nt] = __builtin_amdgcn_mfma_f32_16x16x32_bf16(a, b, acc[nt], 0, 0, 0);
        }
    }
#pragma unroll
    for (int kt = 0; kt < KT; ++kt) {
        bf16x8 a;
        if constexpr (DSTF) a = cvt8((const float*)Xdst_ + (size_t)(m0 + l15) * KF + kt * 32 + quad * 8);
        else                a = *reinterpret_cast<const bf16x8*>((const u16*)Xdst_ + (size_t)(m0 + l15) * KF + kt * 32 + quad * 8);
#pragma unroll
        for (int nt = 0; nt < 8; ++nt) {
            bf16x8 b = *reinterpret_cast<const bf16x8*>(Wrp + (size_t)(((kt * 8 + nt) * 64 + lane) * 8));
            acc[nt] = __builtin_amdgcn_mfma_f32_16x16x32_bf16(a, b, acc[nt], 0, 0, 0);
        }
    }
#pragma unroll
    for (int nt = 0; nt < 8; ++nt) {
        int col = nt * 16 + l15;
        float bv = bias[col];
#pragma unroll
        for (int r = 0; r < 4; ++r) {
            int row = m0 + quad * 4 + r;
            float v = fmaxf(acc[nt][r] + bv, 0.f);
            if constexpr (OUTF) ((float*)out_)[(size_t)row * 128 + col] = v;
            else                ((u16*)out_)[(size_t)row * 128 + col] = f2bf(v);
            if constexpr (SHADOW) out_bf[(size_t)row * 128 + col] = f2bf(v);
        }
    }
}

// ---------------- fused classifier + risk heads (X fp32) ----------------
__global__ void __launch_bounds__(256) head_fused(
    const float* __restrict__ X, const u16* __restrict__ W1p,
    const float* __restrict__ b1a, const float* __restrict__ b1b,
    const float* __restrict__ cW2, const float* __restrict__ cb2,
    const float* __restrict__ rW2, const float* __restrict__ rb2,
    float* __restrict__ pred, float* __restrict__ risk, int M)
{
    __shared__ alignas(16) u16 lds[4][16][128 + LDS_PAD];
    const int lane = threadIdx.x & 63;
    const int wv = threadIdx.x >> 6;
    const int m0 = (blockIdx.x * 4 + wv) * 16;
    const bool active = (m0 < M);
    const int quad = lane >> 4;
    const int l15 = lane & 15;

    if (active) {
        f32x4 acc[8];
#pragma unroll
        for (int i = 0; i < 8; ++i) acc[i] = (f32x4){0.f, 0.f, 0.f, 0.f};
#pragma unroll
        for (int kt = 0; kt < 4; ++kt) {
            bf16x8 a = cvt8(X + (size_t)(m0 + l15) * 128 + kt * 32 + quad * 8);
#pragma unroll
            for (int nt = 0; nt < 8; ++nt) {
                bf16x8 b = *reinterpret_cast<const bf16x8*>(W1p + (size_t)(((kt * 8 + nt) * 64 + lane) * 8));
                acc[nt] = __builtin_amdgcn_mfma_f32_16x16x32_bf16(a, b, acc[nt], 0, 0, 0);
            }
        }
#pragma unroll
        for (int nt = 0; nt < 8; ++nt) {
            int col = nt * 16 + l15;
            float bv = (col < 64) ? b1a[col] : b1b[col - 64];
#pragma unroll
            for (int r = 0; r < 4; ++r) {
                float v = fmaxf(acc[nt][r] + bv, 0.f);
                lds[wv][quad * 4 + r][col] = f2bf(v);
            }
        }
    }
    __syncthreads();
    if (!active) return;

    float w0 = cW2[lane * 2 + 0];
    float w1 = cW2[lane * 2 + 1];
    float w2 = rW2[lane];
    float cb0 = cb2[0], cb1v = cb2[1], rb = rb2[0];
    for (int r = 0; r < 16; ++r) {
        float t1 = bf2f(lds[wv][r][lane]);
        float t2 = bf2f(lds[wv][r][64 + lane]);
        float s0 = t1 * w0;
        float s1 = t1 * w1;
        float s2 = t2 * w2;
        for (int off = 32; off > 0; off >>= 1) {
            s0 += __shfl_xor(s0, off);
            s1 += __shfl_xor(s1, off);
            s2 += __shfl_xor(s2, off);
        }
        if (lane == 0) {
            int row = m0 + r;
            pred[(size_t)row * 2 + 0] = s0 + cb0;
            pred[(size_t)row * 2 + 1] = s1 + cb1v;
            float z = s2 + rb;
            risk[row] = 1.f / (1.f + __expf(-z));
        }
    }
}

// ---------------- host ----------------
#define OFF_CNT_M  ((size_t)0)
#define OFF_CNT_C  ((size_t)262144)
#define OFF_BKT_M  ((size_t)1  << 20)
#define OFF_BKT_C  ((size_t)14 << 20)
#define OFF_HM     ((size_t)27 << 20)
#define OFF_PACK   ((size_t)40 << 20)
#define OFF_XC     ((size_t)41 << 20)
#define OFF_XM     ((size_t)54 << 20)
#define OFF_HCB    ((size_t)61 << 20)
#define WS_SHADOW_NEED ((size_t)87 << 20)

extern "C" void kernel_launch(void* const* d_in, const int* in_sizes, int n_in,
                              void* d_out, int out_size, void* d_ws, size_t ws_size,
                              hipStream_t stream)
{
    const float* x_card   = (const float*)d_in[0];
    const float* x_merch  = (const float*)d_in[1];
    const int* src_cm     = (const int*)d_in[2];
    const int* dst_cm     = (const int*)d_in[3];
    const int* src_mc     = (const int*)d_in[4];
    const int* dst_mc     = (const int*)d_in[5];
    const float* Wl0_cm   = (const float*)d_in[6];
    const float* bl0_cm   = (const float*)d_in[7];
    const float* Wr0_cm   = (const float*)d_in[8];
    const float* Wl0_mc   = (const float*)d_in[9];
    const float* bl0_mc   = (const float*)d_in[10];
    const float* Wr0_mc   = (const float*)d_in[11];
    const float* Wl1_cm   = (const float*)d_in[12];
    const float* bl1_cm   = (const float*)d_in[13];
    const float* Wr1_cm   = (const float*)d_in[14];
    const float* Wl1_mc   = (const float*)d_in[15];
    const float* bl1_mc   = (const float*)d_in[16];
    const float* Wr1_mc   = (const float*)d_in[17];
    const float* cW1_card = (const float*)d_in[18];
    const float* cb1_card = (const float*)d_in[19];
    const float* cW2_card = (const float*)d_in[20];
    const float* cb2_card = (const float*)d_in[21];
    const float* cW1_mer  = (const float*)d_in[22];
    const float* cb1_mer  = (const float*)d_in[23];
    const float* cW2_mer  = (const float*)d_in[24];
    const float* cb2_mer  = (const float*)d_in[25];
    const float* rW1      = (const float*)d_in[26];
    const float* rb1      = (const float*)d_in[27];
    const float* rW2      = (const float*)d_in[28];
    const float* rb2      = (const float*)d_in[29];

    const int nCard  = in_sizes[0] / 64;   // 100000
    const int nMerch = in_sizes[1] / 64;   // 50000
    const int E      = in_sizes[2];        // 1000000

    char* ws = (char*)d_ws;
    int* cnt_m    = (int*)(ws + OFF_CNT_M);
    int* cnt_c    = (int*)(ws + OFF_CNT_C);
    u32* bucket_m = (u32*)(ws + OFF_BKT_M);
    u16* bucket_c = (u16*)(ws + OFF_BKT_C);
    u16* h_m      = (u16*)(ws + OFF_HM);
    u16* pw       = (u16*)(ws + OFF_PACK);
    u16* pWl0_cm = pw + 0 * 16384;
    u16* pWr0_cm = pw + 1 * 16384;
    u16* pWl0_mc = pw + 2 * 16384;
    u16* pWr0_mc = pw + 3 * 16384;
    u16* pWl1_cm = pw + 4 * 16384;
    u16* pWr1_cm = pw + 5 * 16384;
    u16* pWl1_mc = pw + 6 * 16384;
    u16* pWr1_mc = pw + 7 * 16384;
    u16* pHeadC  = pw + 8 * 16384;
    u16* pHeadM  = pw + 9 * 16384;
    u16* xc_bf   = (u16*)(ws + OFF_XC);
    u16* xm_bf   = (u16*)(ws + OFF_XM);
    u16* hc_bf   = (u16*)(ws + OFF_HCB);

    const bool shadow = (ws_size >= WS_SHADOW_NEED);

    float* out     = (float*)d_out;
    float* o_hc2   = out;
    float* o_hm2   = o_hc2 + (size_t)nCard * 128;
    float* o_predc = o_hm2 + (size_t)nMerch * 128;
    float* o_predm = o_predc + (size_t)nCard * 2;
    float* o_riskc = o_predm + (size_t)nMerch * 2;
    float* o_riskm = o_riskc + (size_t)nCard;

    PackArgs pa;
    pa.d[0]  = { Wl0_cm,   pWl0_cm,  64, 128, 0 };
    pa.d[1]  = { Wr0_cm,   pWr0_cm,  64, 128, 0 };
    pa.d[2]  = { Wl0_mc,   pWl0_mc,  64, 128, 0 };
    pa.d[3]  = { Wr0_mc,   pWr0_mc,  64, 128, 0 };
    pa.d[4]  = { Wl1_cm,   pWl1_cm, 128, 128, 0 };
    pa.d[5]  = { Wr1_cm,   pWr1_cm, 128, 128, 0 };
    pa.d[6]  = { Wl1_mc,   pWl1_mc, 128, 128, 0 };
    pa.d[7]  = { Wr1_mc,   pWr1_mc, 128, 128, 0 };
    pa.d[8]  = { cW1_card, pHeadC,  128,  64, 0 };
    pa.d[9]  = { rW1,      pHeadC,  128,  64, 4 };
    pa.d[10] = { cW1_mer,  pHeadM,  128,  64, 0 };
    pa.d[11] = { rW1,      pHeadM,  128,  64, 4 };
    pack_all<<<dim3(64, 12), 256, 0, stream>>>(pa);

    build_buckets_part<<<2 * NPART, 256, 0, stream>>>(
        src_cm, dst_cm, src_mc, dst_mc, cnt_m, bucket_m, cnt_c, bucket_c,
        E, nMerch, nCard);

    if (shadow) {
        f32_to_bf16<<<(nCard * 64 / 4 + 255) / 256, 256, 0, stream>>>(x_card, xc_bf, nCard * 64);
        f32_to_bf16<<<(nMerch * 64 / 4 + 255) / 256, 256, 0, stream>>>(x_merch, xm_bf, nMerch * 64);

        // ---- layer 0 (all gathers bf16) ----
        sage_fused<u32, 64, false, false, false, false><<<(nMerch + 63) / 64, 256, 0, stream>>>(
            xc_bf, bucket_m, cnt_m, pWl0_cm, xm_bf, pWr0_cm, bl0_cm, h_m, nullptr, nMerch);
        sage_fused<u16, 64, false, false, true, true><<<(nCard + 63) / 64, 256, 0, stream>>>(
            xm_bf, bucket_c, cnt_c, pWl0_mc, xc_bf, pWr0_mc, bl0_mc, o_hc2, hc_bf, nCard);

        // ---- layer 1 ----
        sage_fused<u32, 128, false, false, true, false><<<(nMerch + 63) / 64, 256, 0, stream>>>(
            hc_bf, bucket_m, cnt_m, pWl1_cm, h_m, pWr1_cm, bl1_cm, o_hm2, nullptr, nMerch);
        sage_fused<u16, 128, false, false, true, false><<<(nCard + 63) / 64, 256, 0, stream>>>(
            h_m, bucket_c, cnt_c, pWl1_mc, hc_bf, pWr1_mc, bl1_mc, o_hc2, nullptr, nCard);
    } else {
        // fallback: fp32 gathers, in-place h_c update (row-disjoint)
        sage_fused<u32, 64, true, true, false, false><<<(nMerch + 63) / 64, 256, 0, stream>>>(
            x_card, bucket_m, cnt_m, pWl0_cm, x_merch, pWr0_cm, bl0_cm, h_m, nullptr, nMerch);
        sage_fused<u16, 64, true, true, true, false><<<(nCard + 63) / 64, 256, 0, stream>>>(
            x_merch, bucket_c, cnt_c, pWl0_mc, x_card, pWr0_mc, bl0_mc, o_hc2, nullptr, nCard);
        sage_fused<u32, 128, true, false, true, false><<<(nMerch + 63) / 64, 256, 0, stream>>>(
            o_hc2, bucket_m, cnt_m, pWl1_cm, h_m, pWr1_cm, bl1_cm, o_hm2, nullptr, nMerch);
        sage_fused<u16, 128, false, true, true, false><<<(nCard + 63) / 64, 256, 0, stream>>>(
            h_m, bucket_c, cnt_c, pWl1_mc, o_hc2, pWr1_mc, bl1_mc, o_hc2, nullptr, nCard);
    }

    // ---- heads ----
    head_fused<<<(nCard + 63) / 64, 256, 0, stream>>>(
        o_hc2, pHeadC, cb1_card, rb1, cW2_card, cb2_card, rW2, rb2, o_predc, o_riskc, nCard);
    head_fused<<<(nMerch + 63) / 64, 256, 0, stream>>>(
        o_hm2, pHeadM, cb1_mer, rb1, cW2_mer, cb2_mer, rW2, rb2, o_predm, o_riskm, nMerch);
}

// Round 6
// 672.573 us; speedup vs baseline: 2.8235x; 2.8235x over previous
//
#include <hip/hip_runtime.h>

// HeteroGraphSAGE on MI355X — fp32 I/O, bf16 MFMA internals.
// R6: bucket build = XCD-partitioned dst ranges (flat blockId % 8 -> XCD
// heuristic keeps each range's bucket lines in one XCD's L2) x 32 edge-chunks
// -> 512 blocks (R5's 64-block version was occupancy-starved at 3%).
// Slot assignment via global atomics (cheap per R4). Shadow-bf16 gathers kept.
//
// ws layout (bytes):
//   cnt_m    @ 0        (50000*4)
//   cnt_c    @ 256K     (100000*4)
//   bucket_m @ 1  MiB   (50000*64*4  u32 card ids)
//   bucket_c @ 14 MiB   (100000*64*2 u16 merchant ids)
//   h_m      @ 27 MiB   (50000*128*2 bf16)
//   packed   @ 40 MiB   (10 * 32 KiB bf16)
//   -- shadow region (only if ws_size >= 87 MiB) --
//   xc_bf    @ 41 MiB   (12.8 MB)   xm_bf @ 54 MiB (6.4 MB)   hc_bf @ 61 MiB (25.6 MB)

typedef unsigned short u16;
typedef unsigned int u32;
typedef short bf16x8 __attribute__((ext_vector_type(8)));
typedef float f32x4 __attribute__((ext_vector_type(4)));
typedef u16 u16x4 __attribute__((ext_vector_type(4)));
typedef u16 u16x8 __attribute__((ext_vector_type(8)));

#define CAP 64
#define LDS_PAD 8
#define NXCD 8     // dst-space partitions (one per XCD)
#define ECHUNK 32  // edge-list chunks per partition

__device__ __forceinline__ float bf2f(u16 u) {
    union { u32 i; float f; } v; v.i = ((u32)u) << 16; return v.f;
}
__device__ __forceinline__ u16 f2bf(float f) {
    union { float f; u32 i; } v; v.f = f;
    u32 i = v.i;
    return (u16)((i + 0x7FFFu + ((i >> 16) & 1u)) >> 16);   // RNE
}
__device__ __forceinline__ bf16x8 cvt8(const float* p) {
    bf16x8 r;
#pragma unroll
    for (int i = 0; i < 8; ++i) r[i] = (short)f2bf(p[i]);
    return r;
}

// ---------------- weight packing: fp32 W[K,Nsrc] -> bf16 MFMA B fragments ----------------
struct PackDesc { const float* src; u16* dst; int K; int Nsrc; int ntOff; };
struct PackArgs { PackDesc d[12]; };

__global__ void __launch_bounds__(256) pack_all(PackArgs pa) {
    PackDesc pd = pa.d[blockIdx.y];
    int idx = blockIdx.x * 256 + threadIdx.x;          // < 16384
    int j = idx & 7;
    int lane = (idx >> 3) & 63;
    int t = idx >> 9;
    int nLocal = pd.Nsrc >> 4;
    int ntl = t % nLocal;
    int kt = t / nLocal;
    if (kt >= (pd.K >> 5)) return;
    int k = kt * 32 + ((lane >> 4) << 3) + j;
    int n = ntl * 16 + (lane & 15);
    pd.dst[(((kt * 8 + pd.ntOff + ntl) * 64) + lane) * 8 + j] = f2bf(pd.src[k * pd.Nsrc + n]);
}

// ---------------- fp32 -> bf16 shadow conversion ----------------
__global__ void __launch_bounds__(256) f32_to_bf16(
    const float* __restrict__ a, u16* __restrict__ b, int n)   // n % 4 == 0
{
    int i = (blockIdx.x * 256 + threadIdx.x) * 4;
    if (i >= n) return;
    f32x4 v = *reinterpret_cast<const f32x4*>(a + i);
    u16x4 o;
#pragma unroll
    for (int j = 0; j < 4; ++j) o[j] = f2bf(v[j]);
    *reinterpret_cast<u16x4*>(b + i) = o;
}

// ---------------- XCD-partitioned bucket build ----------------
// grid = (NXCD, ECHUNK, 2). xcdGroup = blockIdx.x = flatId % NXCD -> same-XCD
// blocks own one contiguous dst range; bucket lines of that range stay in the
// local L2 until fully populated. Edge chunks give 512-block parallelism.
__global__ void __launch_bounds__(256) build_buckets_xcd(
    const int* __restrict__ src_cm, const int* __restrict__ dst_cm,
    const int* __restrict__ src_mc, const int* __restrict__ dst_mc,
    int* __restrict__ cnt_m, u32* __restrict__ bucket_m,
    int* __restrict__ cnt_c, u16* __restrict__ bucket_c,
    int E, int nMerch, int nCard)
{
    const int g = blockIdx.x;                 // dst partition / XCD group
    const int chunk = blockIdx.y;
    const bool dirA = (blockIdx.z == 0);      // A: dst_cm -> merchants
    const int nNode = dirA ? nMerch : nCard;
    const int lo = (int)((long long)g * nNode / NXCD);
    const int hi = (int)((long long)(g + 1) * nNode / NXCD);
    const int* dst = dirA ? dst_cm : dst_mc;
    const int* src = dirA ? src_cm : src_mc;
    int* cnt = dirA ? cnt_m : cnt_c;
    const int e0 = (int)((long long)chunk * E / ECHUNK);
    const int e1 = (int)((long long)(chunk + 1) * E / ECHUNK);

    for (int i = e0 + threadIdx.x; i < e1; i += 256) {
        int d = dst[i];
        if (d >= lo && d < hi) {
            int slot = atomicAdd(&cnt[d], 1);
            if (slot < CAP) {
                int s = src[i];
                if (dirA) bucket_m[(size_t)d * CAP + slot] = (u32)s;
                else      bucket_c[(size_t)d * CAP + slot] = (u16)s;
            }
        }
    }
}

// ---------------- fused SAGE layer ----------------
// out[M,128] = relu(mean_nbr(Xsrc) @ Wl + Xdst @ Wr + bias)
// Gather: 4 neighbor-groups x 16 feature-lanes x 2 banks (8 nbrs/step).
// SRCF/DSTF: fp32 (true) or bf16 (false). OUTF: fp32 out. SHADOW: also write bf16 copy.
template<typename IdxT, int KF, bool SRCF, bool DSTF, bool OUTF, bool SHADOW>
__global__ void __launch_bounds__(256) sage_fused(
    const void* __restrict__ Xsrc_, const IdxT* __restrict__ adj,
    const int* __restrict__ cnt,
    const u16* __restrict__ Wlp, const void* __restrict__ Xdst_,
    const u16* __restrict__ Wrp, const float* __restrict__ bias,
    void* __restrict__ out_, u16* __restrict__ out_bf, int M)
{
    constexpr int NV = KF / 16;         // values per lane per neighbor
    __shared__ alignas(16) u16 lds[4][16][128 + LDS_PAD];
    const int lane = threadIdx.x & 63;
    const int wv = threadIdx.x >> 6;
    const int m0 = (blockIdx.x * 4 + wv) * 16;
    const bool active = (m0 < M);
    const int quad = lane >> 4;
    const int l15 = lane & 15;
    const int nb = quad;
    const int fl = l15;

    if (active) {
        const float* srcF = (const float*)Xsrc_;
        const u16*   srcH = (const u16*)Xsrc_;
        for (int r = 0; r < 16; ++r) {
            int node = m0 + r;
            int c = cnt[node];
            int cc = min(c, CAP);
            int sidx = (lane < cc) ? (int)adj[(size_t)node * CAP + lane] : 0;
            float inv = 1.f / (float)max(c, 1);
            float acc0[NV], acc1[NV];
#pragma unroll
            for (int i = 0; i < NV; ++i) { acc0[i] = 0.f; acc1[i] = 0.f; }
            for (int t = 0; t < cc; t += 8) {
                int k0 = t + nb;
                int k1 = t + nb + 4;
                int s0 = __shfl(sidx, k0);
                int s1 = __shfl(sidx, k1);
                bool p0 = k0 < cc;
                bool p1 = k1 < cc;
                if constexpr (SRCF) {
                    const f32x4* q0 = (const f32x4*)(srcF + (size_t)s0 * KF + fl * NV);
                    const f32x4* q1 = (const f32x4*)(srcF + (size_t)s1 * KF + fl * NV);
                    f32x4 u0 = q0[0];
                    f32x4 u1 = q1[0];
                    if constexpr (NV == 8) {
                        f32x4 w0 = q0[1];
                        f32x4 w1 = q1[1];
#pragma unroll
                        for (int i = 0; i < 4; ++i) {
                            acc0[4 + i] += p0 ? w0[i] : 0.f;
                            acc1[4 + i] += p1 ? w1[i] : 0.f;
                        }
                    }
#pragma unroll
                    for (int i = 0; i < 4; ++i) {
                        acc0[i] += p0 ? u0[i] : 0.f;
                        acc1[i] += p1 ? u1[i] : 0.f;
                    }
                } else {
                    if constexpr (NV == 8) {
                        bf16x8 u0 = *(const bf16x8*)(srcH + (size_t)s0 * KF + fl * 8);
                        bf16x8 u1 = *(const bf16x8*)(srcH + (size_t)s1 * KF + fl * 8);
#pragma unroll
                        for (int i = 0; i < 8; ++i) {
                            acc0[i] += p0 ? bf2f((u16)u0[i]) : 0.f;
                            acc1[i] += p1 ? bf2f((u16)u1[i]) : 0.f;
                        }
                    } else {
                        u16x4 u0 = *(const u16x4*)(srcH + (size_t)s0 * KF + fl * 4);
                        u16x4 u1 = *(const u16x4*)(srcH + (size_t)s1 * KF + fl * 4);
#pragma unroll
                        for (int i = 0; i < 4; ++i) {
                            acc0[i] += p0 ? bf2f(u0[i]) : 0.f;
                            acc1[i] += p1 ? bf2f(u1[i]) : 0.f;
                        }
                    }
                }
            }
            u16 packed[NV];
#pragma unroll
            for (int i = 0; i < NV; ++i) {
                float m = acc0[i] + acc1[i];
                m += __shfl_xor(m, 16);
                m += __shfl_xor(m, 32);
                packed[i] = f2bf(m * inv);
            }
            if (nb == 0) {
                if constexpr (NV == 8) *(u16x8*)&lds[wv][r][fl * 8] = *(const u16x8*)packed;
                else                   *(u16x4*)&lds[wv][r][fl * 4] = *(const u16x4*)packed;
            }
        }
    }
    __syncthreads();
    if (!active) return;

    constexpr int KT = KF >> 5;
    f32x4 acc[8];
#pragma unroll
    for (int i = 0; i < 8; ++i) acc[i] = (f32x4){0.f, 0.f, 0.f, 0.f};

#pragma unroll
    for (int kt = 0; kt < KT; ++kt) {
        bf16x8 a = *reinterpret_cast<const bf16x8*>(&lds[wv][l15][kt * 32 + quad * 8]);
#pragma unroll
        for (int nt = 0; nt < 8; ++nt) {
            bf16x8 b = *reinterpret_cast<const bf16x8*>(Wlp + (size_t)(((kt * 8 + nt) * 64 + lane) * 8));
            acc[nt] = __builtin_amdgcn_mfma_f32_16x16x32_bf16(a, b, acc[nt], 0, 0, 0);
        }
    }
#pragma unroll
    for (int kt = 0; kt < KT; ++kt) {
        bf16x8 a;
        if constexpr (DSTF) a = cvt8((const float*)Xdst_ + (size_t)(m0 + l15) * KF + kt * 32 + quad * 8);
        else                a = *reinterpret_cast<const bf16x8*>((const u16*)Xdst_ + (size_t)(m0 + l15) * KF + kt * 32 + quad * 8);
#pragma unroll
        for (int nt = 0; nt < 8; ++nt) {
            bf16x8 b = *reinterpret_cast<const bf16x8*>(Wrp + (size_t)(((kt * 8 + nt) * 64 + lane) * 8));
            acc[nt] = __builtin_amdgcn_mfma_f32_16x16x32_bf16(a, b, acc[nt], 0, 0, 0);
        }
    }
#pragma unroll
    for (int nt = 0; nt < 8; ++nt) {
        int col = nt * 16 + l15;
        float bv = bias[col];
#pragma unroll
        for (int r = 0; r < 4; ++r) {
            int row = m0 + quad * 4 + r;
            float v = fmaxf(acc[nt][r] + bv, 0.f);
            if constexpr (OUTF) ((float*)out_)[(size_t)row * 128 + col] = v;
            else                ((u16*)out_)[(size_t)row * 128 + col] = f2bf(v);
            if constexpr (SHADOW) out_bf[(size_t)row * 128 + col] = f2bf(v);
        }
    }
}

// ---------------- fused classifier + risk heads (X fp32) ----------------
__global__ void __launch_bounds__(256) head_fused(
    const float* __restrict__ X, const u16* __restrict__ W1p,
    const float* __restrict__ b1a, const float* __restrict__ b1b,
    const float* __restrict__ cW2, const float* __restrict__ cb2,
    const float* __restrict__ rW2, const float* __restrict__ rb2,
    float* __restrict__ pred, float* __restrict__ risk, int M)
{
    __shared__ alignas(16) u16 lds[4][16][128 + LDS_PAD];
    const int lane = threadIdx.x & 63;
    const int wv = threadIdx.x >> 6;
    const int m0 = (blockIdx.x * 4 + wv) * 16;
    const bool active = (m0 < M);
    const int quad = lane >> 4;
    const int l15 = lane & 15;

    if (active) {
        f32x4 acc[8];
#pragma unroll
        for (int i = 0; i < 8; ++i) acc[i] = (f32x4){0.f, 0.f, 0.f, 0.f};
#pragma unroll
        for (int kt = 0; kt < 4; ++kt) {
            bf16x8 a = cvt8(X + (size_t)(m0 + l15) * 128 + kt * 32 + quad * 8);
#pragma unroll
            for (int nt = 0; nt < 8; ++nt) {
                bf16x8 b = *reinterpret_cast<const bf16x8*>(W1p + (size_t)(((kt * 8 + nt) * 64 + lane) * 8));
                acc[nt] = __builtin_amdgcn_mfma_f32_16x16x32_bf16(a, b, acc[nt], 0, 0, 0);
            }
        }
#pragma unroll
        for (int nt = 0; nt < 8; ++nt) {
            int col = nt * 16 + l15;
            float bv = (col < 64) ? b1a[col] : b1b[col - 64];
#pragma unroll
            for (int r = 0; r < 4; ++r) {
                float v = fmaxf(acc[nt][r] + bv, 0.f);
                lds[wv][quad * 4 + r][col] = f2bf(v);
            }
        }
    }
    __syncthreads();
    if (!active) return;

    float w0 = cW2[lane * 2 + 0];
    float w1 = cW2[lane * 2 + 1];
    float w2 = rW2[lane];
    float cb0 = cb2[0], cb1v = cb2[1], rb = rb2[0];
    for (int r = 0; r < 16; ++r) {
        float t1 = bf2f(lds[wv][r][lane]);
        float t2 = bf2f(lds[wv][r][64 + lane]);
        float s0 = t1 * w0;
        float s1 = t1 * w1;
        float s2 = t2 * w2;
        for (int off = 32; off > 0; off >>= 1) {
            s0 += __shfl_xor(s0, off);
            s1 += __shfl_xor(s1, off);
            s2 += __shfl_xor(s2, off);
        }
        if (lane == 0) {
            int row = m0 + r;
            pred[(size_t)row * 2 + 0] = s0 + cb0;
            pred[(size_t)row * 2 + 1] = s1 + cb1v;
            float z = s2 + rb;
            risk[row] = 1.f / (1.f + __expf(-z));
        }
    }
}

// ---------------- host ----------------
#define OFF_CNT_M  ((size_t)0)
#define OFF_CNT_C  ((size_t)262144)
#define OFF_BKT_M  ((size_t)1  << 20)
#define OFF_BKT_C  ((size_t)14 << 20)
#define OFF_HM     ((size_t)27 << 20)
#define OFF_PACK   ((size_t)40 << 20)
#define OFF_XC     ((size_t)41 << 20)
#define OFF_XM     ((size_t)54 << 20)
#define OFF_HCB    ((size_t)61 << 20)
#define WS_SHADOW_NEED ((size_t)87 << 20)

extern "C" void kernel_launch(void* const* d_in, const int* in_sizes, int n_in,
                              void* d_out, int out_size, void* d_ws, size_t ws_size,
                              hipStream_t stream)
{
    const float* x_card   = (const float*)d_in[0];
    const float* x_merch  = (const float*)d_in[1];
    const int* src_cm     = (const int*)d_in[2];
    const int* dst_cm     = (const int*)d_in[3];
    const int* src_mc     = (const int*)d_in[4];
    const int* dst_mc     = (const int*)d_in[5];
    const float* Wl0_cm   = (const float*)d_in[6];
    const float* bl0_cm   = (const float*)d_in[7];
    const float* Wr0_cm   = (const float*)d_in[8];
    const float* Wl0_mc   = (const float*)d_in[9];
    const float* bl0_mc   = (const float*)d_in[10];
    const float* Wr0_mc   = (const float*)d_in[11];
    const float* Wl1_cm   = (const float*)d_in[12];
    const float* bl1_cm   = (const float*)d_in[13];
    const float* Wr1_cm   = (const float*)d_in[14];
    const float* Wl1_mc   = (const float*)d_in[15];
    const float* bl1_mc   = (const float*)d_in[16];
    const float* Wr1_mc   = (const float*)d_in[17];
    const float* cW1_card = (const float*)d_in[18];
    const float* cb1_card = (const float*)d_in[19];
    const float* cW2_card = (const float*)d_in[20];
    const float* cb2_card = (const float*)d_in[21];
    const float* cW1_mer  = (const float*)d_in[22];
    const float* cb1_mer  = (const float*)d_in[23];
    const float* cW2_mer  = (const float*)d_in[24];
    const float* cb2_mer  = (const float*)d_in[25];
    const float* rW1      = (const float*)d_in[26];
    const float* rb1      = (const float*)d_in[27];
    const float* rW2      = (const float*)d_in[28];
    const float* rb2      = (const float*)d_in[29];

    const int nCard  = in_sizes[0] / 64;   // 100000
    const int nMerch = in_sizes[1] / 64;   // 50000
    const int E      = in_sizes[2];        // 1000000

    char* ws = (char*)d_ws;
    int* cnt_m    = (int*)(ws + OFF_CNT_M);
    int* cnt_c    = (int*)(ws + OFF_CNT_C);
    u32* bucket_m = (u32*)(ws + OFF_BKT_M);
    u16* bucket_c = (u16*)(ws + OFF_BKT_C);
    u16* h_m      = (u16*)(ws + OFF_HM);
    u16* pw       = (u16*)(ws + OFF_PACK);
    u16* pWl0_cm = pw + 0 * 16384;
    u16* pWr0_cm = pw + 1 * 16384;
    u16* pWl0_mc = pw + 2 * 16384;
    u16* pWr0_mc = pw + 3 * 16384;
    u16* pWl1_cm = pw + 4 * 16384;
    u16* pWr1_cm = pw + 5 * 16384;
    u16* pWl1_mc = pw + 6 * 16384;
    u16* pWr1_mc = pw + 7 * 16384;
    u16* pHeadC  = pw + 8 * 16384;
    u16* pHeadM  = pw + 9 * 16384;
    u16* xc_bf   = (u16*)(ws + OFF_XC);
    u16* xm_bf   = (u16*)(ws + OFF_XM);
    u16* hc_bf   = (u16*)(ws + OFF_HCB);

    const bool shadow = (ws_size >= WS_SHADOW_NEED);

    float* out     = (float*)d_out;
    float* o_hc2   = out;
    float* o_hm2   = o_hc2 + (size_t)nCard * 128;
    float* o_predc = o_hm2 + (size_t)nMerch * 128;
    float* o_predm = o_predc + (size_t)nCard * 2;
    float* o_riskc = o_predm + (size_t)nMerch * 2;
    float* o_riskm = o_riskc + (size_t)nCard;

    // zero the two count arrays (required: build uses global atomicAdd)
    hipMemsetAsync(ws, 0, OFF_CNT_C + (size_t)nCard * sizeof(int), stream);

    PackArgs pa;
    pa.d[0]  = { Wl0_cm,   pWl0_cm,  64, 128, 0 };
    pa.d[1]  = { Wr0_cm,   pWr0_cm,  64, 128, 0 };
    pa.d[2]  = { Wl0_mc,   pWl0_mc,  64, 128, 0 };
    pa.d[3]  = { Wr0_mc,   pWr0_mc,  64, 128, 0 };
    pa.d[4]  = { Wl1_cm,   pWl1_cm, 128, 128, 0 };
    pa.d[5]  = { Wr1_cm,   pWr1_cm, 128, 128, 0 };
    pa.d[6]  = { Wl1_mc,   pWl1_mc, 128, 128, 0 };
    pa.d[7]  = { Wr1_mc,   pWr1_mc, 128, 128, 0 };
    pa.d[8]  = { cW1_card, pHeadC,  128,  64, 0 };
    pa.d[9]  = { rW1,      pHeadC,  128,  64, 4 };
    pa.d[10] = { cW1_mer,  pHeadM,  128,  64, 0 };
    pa.d[11] = { rW1,      pHeadM,  128,  64, 4 };
    pack_all<<<dim3(64, 12), 256, 0, stream>>>(pa);

    build_buckets_xcd<<<dim3(NXCD, ECHUNK, 2), 256, 0, stream>>>(
        src_cm, dst_cm, src_mc, dst_mc, cnt_m, bucket_m, cnt_c, bucket_c,
        E, nMerch, nCard);

    if (shadow) {
        f32_to_bf16<<<(nCard * 64 / 4 + 255) / 256, 256, 0, stream>>>(x_card, xc_bf, nCard * 64);
        f32_to_bf16<<<(nMerch * 64 / 4 + 255) / 256, 256, 0, stream>>>(x_merch, xm_bf, nMerch * 64);

        // ---- layer 0 (all gathers bf16) ----
        sage_fused<u32, 64, false, false, false, false><<<(nMerch + 63) / 64, 256, 0, stream>>>(
            xc_bf, bucket_m, cnt_m, pWl0_cm, xm_bf, pWr0_cm, bl0_cm, h_m, nullptr, nMerch);
        sage_fused<u16, 64, false, false, true, true><<<(nCard + 63) / 64, 256, 0, stream>>>(
            xm_bf, bucket_c, cnt_c, pWl0_mc, xc_bf, pWr0_mc, bl0_mc, o_hc2, hc_bf, nCard);

        // ---- layer 1 ----
        sage_fused<u32, 128, false, false, true, false><<<(nMerch + 63) / 64, 256, 0, stream>>>(
            hc_bf, bucket_m, cnt_m, pWl1_cm, h_m, pWr1_cm, bl1_cm, o_hm2, nullptr, nMerch);
        sage_fused<u16, 128, false, false, true, false><<<(nCard + 63) / 64, 256, 0, stream>>>(
            h_m, bucket_c, cnt_c, pWl1_mc, hc_bf, pWr1_mc, bl1_mc, o_hc2, nullptr, nCard);
    } else {
        // fallback: fp32 gathers, in-place h_c update (row-disjoint)
        sage_fused<u32, 64, true, true, false, false><<<(nMerch + 63) / 64, 256, 0, stream>>>(
            x_card, bucket_m, cnt_m, pWl0_cm, x_merch, pWr0_cm, bl0_cm, h_m, nullptr, nMerch);
        sage_fused<u16, 64, true, true, true, false><<<(nCard + 63) / 64, 256, 0, stream>>>(
            x_merch, bucket_c, cnt_c, pWl0_mc, x_card, pWr0_mc, bl0_mc, o_hc2, nullptr, nCard);
        sage_fused<u32, 128, true, false, true, false><<<(nMerch + 63) / 64, 256, 0, stream>>>(
            o_hc2, bucket_m, cnt_m, pWl1_cm, h_m, pWr1_cm, bl1_cm, o_hm2, nullptr, nMerch);
        sage_fused<u16, 128, false, true, true, false><<<(nCard + 63) / 64, 256, 0, stream>>>(
            h_m, bucket_c, cnt_c, pWl1_mc, o_hc2, pWr1_mc, bl1_mc, o_hc2, nullptr, nCard);
    }

    // ---- heads ----
    head_fused<<<(nCard + 63) / 64, 256, 0, stream>>>(
        o_hc2, pHeadC, cb1_card, rb1, cW2_card, cb2_card, rW2, rb2, o_predc, o_riskc, nCard);
    head_fused<<<(nMerch + 63) / 64, 256, 0, stream>>>(
        o_hm2, pHeadM, cb1_mer, rb1, cW2_mer, cb2_mer, rW2, rb2, o_predm, o_riskm, nMerch);
}

// Round 7
// 617.125 us; speedup vs baseline: 3.0772x; 1.0898x over previous
//
#include <hip/hip_runtime.h>

// HeteroGraphSAGE on MI355X — fp32 I/O, bf16 MFMA internals.
// R7: build = R6 XCD-partitioned structure + NONTEMPORAL edge loads (stop the
// 62MB edge stream from evicting partially-filled bucket lines out of the
// local L2) + ECHUNK 64 (1024 blocks, ~50% occupancy). Rest unchanged.
//
// ws layout (bytes):
//   cnt_m    @ 0        (50000*4)
//   cnt_c    @ 256K     (100000*4)
//   bucket_m @ 1  MiB   (50000*64*4  u32 card ids)
//   bucket_c @ 14 MiB   (100000*64*2 u16 merchant ids)
//   h_m      @ 27 MiB   (50000*128*2 bf16)
//   packed   @ 40 MiB   (10 * 32 KiB bf16)
//   -- shadow region (only if ws_size >= 87 MiB) --
//   xc_bf    @ 41 MiB   (12.8 MB)   xm_bf @ 54 MiB (6.4 MB)   hc_bf @ 61 MiB (25.6 MB)

typedef unsigned short u16;
typedef unsigned int u32;
typedef short bf16x8 __attribute__((ext_vector_type(8)));
typedef float f32x4 __attribute__((ext_vector_type(4)));
typedef u16 u16x4 __attribute__((ext_vector_type(4)));
typedef u16 u16x8 __attribute__((ext_vector_type(8)));

#define CAP 64
#define LDS_PAD 8
#define NXCD 8     // dst-space partitions (one per XCD; flat blockIdx % 8 -> XCD)
#define ECHUNK 64  // edge-list chunks per partition

__device__ __forceinline__ float bf2f(u16 u) {
    union { u32 i; float f; } v; v.i = ((u32)u) << 16; return v.f;
}
__device__ __forceinline__ u16 f2bf(float f) {
    union { float f; u32 i; } v; v.f = f;
    u32 i = v.i;
    return (u16)((i + 0x7FFFu + ((i >> 16) & 1u)) >> 16);   // RNE
}
__device__ __forceinline__ bf16x8 cvt8(const float* p) {
    bf16x8 r;
#pragma unroll
    for (int i = 0; i < 8; ++i) r[i] = (short)f2bf(p[i]);
    return r;
}

// ---------------- weight packing: fp32 W[K,Nsrc] -> bf16 MFMA B fragments ----------------
struct PackDesc { const float* src; u16* dst; int K; int Nsrc; int ntOff; };
struct PackArgs { PackDesc d[12]; };

__global__ void __launch_bounds__(256) pack_all(PackArgs pa) {
    PackDesc pd = pa.d[blockIdx.y];
    int idx = blockIdx.x * 256 + threadIdx.x;          // < 16384
    int j = idx & 7;
    int lane = (idx >> 3) & 63;
    int t = idx >> 9;
    int nLocal = pd.Nsrc >> 4;
    int ntl = t % nLocal;
    int kt = t / nLocal;
    if (kt >= (pd.K >> 5)) return;
    int k = kt * 32 + ((lane >> 4) << 3) + j;
    int n = ntl * 16 + (lane & 15);
    pd.dst[(((kt * 8 + pd.ntOff + ntl) * 64) + lane) * 8 + j] = f2bf(pd.src[k * pd.Nsrc + n]);
}

// ---------------- fp32 -> bf16 shadow conversion ----------------
__global__ void __launch_bounds__(256) f32_to_bf16(
    const float* __restrict__ a, u16* __restrict__ b, int n)   // n % 4 == 0
{
    int i = (blockIdx.x * 256 + threadIdx.x) * 4;
    if (i >= n) return;
    f32x4 v = *reinterpret_cast<const f32x4*>(a + i);
    u16x4 o;
#pragma unroll
    for (int j = 0; j < 4; ++j) o[j] = f2bf(v[j]);
    *reinterpret_cast<u16x4*>(b + i) = o;
}

// ---------------- XCD-partitioned bucket build, nontemporal edge streams ----------------
// grid = (NXCD, ECHUNK, 2). blockIdx.x = flatId % NXCD -> same-XCD blocks own
// one contiguous dst range; nt loads keep the edge stream from evicting the
// partially-filled bucket lines out of that XCD's L2.
__global__ void __launch_bounds__(256) build_buckets_xcd(
    const int* __restrict__ src_cm, const int* __restrict__ dst_cm,
    const int* __restrict__ src_mc, const int* __restrict__ dst_mc,
    int* __restrict__ cnt_m, u32* __restrict__ bucket_m,
    int* __restrict__ cnt_c, u16* __restrict__ bucket_c,
    int E, int nMerch, int nCard)
{
    const int g = blockIdx.x;                 // dst partition / XCD group
    const int chunk = blockIdx.y;
    const bool dirA = (blockIdx.z == 0);      // A: dst_cm -> merchants
    const int nNode = dirA ? nMerch : nCard;
    const int lo = (int)((long long)g * nNode / NXCD);
    const int hi = (int)((long long)(g + 1) * nNode / NXCD);
    const int* dst = dirA ? dst_cm : dst_mc;
    const int* src = dirA ? src_cm : src_mc;
    int* cnt = dirA ? cnt_m : cnt_c;
    const int e0 = (int)((long long)chunk * E / ECHUNK);
    const int e1 = (int)((long long)(chunk + 1) * E / ECHUNK);

    for (int i = e0 + threadIdx.x; i < e1; i += 256) {
        int d = __builtin_nontemporal_load(dst + i);
        if (d >= lo && d < hi) {
            int slot = atomicAdd(&cnt[d], 1);
            if (slot < CAP) {
                int s = __builtin_nontemporal_load(src + i);
                if (dirA) bucket_m[(size_t)d * CAP + slot] = (u32)s;
                else      bucket_c[(size_t)d * CAP + slot] = (u16)s;
            }
        }
    }
}

// ---------------- fused SAGE layer ----------------
// out[M,128] = relu(mean_nbr(Xsrc) @ Wl + Xdst @ Wr + bias)
// Gather: 4 neighbor-groups x 16 feature-lanes x 2 banks (8 nbrs/step).
// SRCF/DSTF: fp32 (true) or bf16 (false). OUTF: fp32 out. SHADOW: also write bf16 copy.
template<typename IdxT, int KF, bool SRCF, bool DSTF, bool OUTF, bool SHADOW>
__global__ void __launch_bounds__(256) sage_fused(
    const void* __restrict__ Xsrc_, const IdxT* __restrict__ adj,
    const int* __restrict__ cnt,
    const u16* __restrict__ Wlp, const void* __restrict__ Xdst_,
    const u16* __restrict__ Wrp, const float* __restrict__ bias,
    void* __restrict__ out_, u16* __restrict__ out_bf, int M)
{
    constexpr int NV = KF / 16;         // values per lane per neighbor
    __shared__ alignas(16) u16 lds[4][16][128 + LDS_PAD];
    const int lane = threadIdx.x & 63;
    const int wv = threadIdx.x >> 6;
    const int m0 = (blockIdx.x * 4 + wv) * 16;
    const bool active = (m0 < M);
    const int quad = lane >> 4;
    const int l15 = lane & 15;
    const int nb = quad;
    const int fl = l15;

    if (active) {
        const float* srcF = (const float*)Xsrc_;
        const u16*   srcH = (const u16*)Xsrc_;
        for (int r = 0; r < 16; ++r) {
            int node = m0 + r;
            int c = cnt[node];
            int cc = min(c, CAP);
            int sidx = (lane < cc) ? (int)adj[(size_t)node * CAP + lane] : 0;
            float inv = 1.f / (float)max(c, 1);
            float acc0[NV], acc1[NV];
#pragma unroll
            for (int i = 0; i < NV; ++i) { acc0[i] = 0.f; acc1[i] = 0.f; }
            for (int t = 0; t < cc; t += 8) {
                int k0 = t + nb;
                int k1 = t + nb + 4;
                int s0 = __shfl(sidx, k0);
                int s1 = __shfl(sidx, k1);
                bool p0 = k0 < cc;
                bool p1 = k1 < cc;
                if constexpr (SRCF) {
                    const f32x4* q0 = (const f32x4*)(srcF + (size_t)s0 * KF + fl * NV);
                    const f32x4* q1 = (const f32x4*)(srcF + (size_t)s1 * KF + fl * NV);
                    f32x4 u0 = q0[0];
                    f32x4 u1 = q1[0];
                    if constexpr (NV == 8) {
                        f32x4 w0 = q0[1];
                        f32x4 w1 = q1[1];
#pragma unroll
                        for (int i = 0; i < 4; ++i) {
                            acc0[4 + i] += p0 ? w0[i] : 0.f;
                            acc1[4 + i] += p1 ? w1[i] : 0.f;
                        }
                    }
#pragma unroll
                    for (int i = 0; i < 4; ++i) {
                        acc0[i] += p0 ? u0[i] : 0.f;
                        acc1[i] += p1 ? u1[i] : 0.f;
                    }
                } else {
                    if constexpr (NV == 8) {
                        bf16x8 u0 = *(const bf16x8*)(srcH + (size_t)s0 * KF + fl * 8);
                        bf16x8 u1 = *(const bf16x8*)(srcH + (size_t)s1 * KF + fl * 8);
#pragma unroll
                        for (int i = 0; i < 8; ++i) {
                            acc0[i] += p0 ? bf2f((u16)u0[i]) : 0.f;
                            acc1[i] += p1 ? bf2f((u16)u1[i]) : 0.f;
                        }
                    } else {
                        u16x4 u0 = *(const u16x4*)(srcH + (size_t)s0 * KF + fl * 4);
                        u16x4 u1 = *(const u16x4*)(srcH + (size_t)s1 * KF + fl * 4);
#pragma unroll
                        for (int i = 0; i < 4; ++i) {
                            acc0[i] += p0 ? bf2f(u0[i]) : 0.f;
                            acc1[i] += p1 ? bf2f(u1[i]) : 0.f;
                        }
                    }
                }
            }
            u16 packed[NV];
#pragma unroll
            for (int i = 0; i < NV; ++i) {
                float m = acc0[i] + acc1[i];
                m += __shfl_xor(m, 16);
                m += __shfl_xor(m, 32);
                packed[i] = f2bf(m * inv);
            }
            if (nb == 0) {
                if constexpr (NV == 8) *(u16x8*)&lds[wv][r][fl * 8] = *(const u16x8*)packed;
                else                   *(u16x4*)&lds[wv][r][fl * 4] = *(const u16x4*)packed;
            }
        }
    }
    __syncthreads();
    if (!active) return;

    constexpr int KT = KF >> 5;
    f32x4 acc[8];
#pragma unroll
    for (int i = 0; i < 8; ++i) acc[i] = (f32x4){0.f, 0.f, 0.f, 0.f};

#pragma unroll
    for (int kt = 0; kt < KT; ++kt) {
        bf16x8 a = *reinterpret_cast<const bf16x8*>(&lds[wv][l15][kt * 32 + quad * 8]);
#pragma unroll
        for (int nt = 0; nt < 8; ++nt) {
            bf16x8 b = *reinterpret_cast<const bf16x8*>(Wlp + (size_t)(((kt * 8 + nt) * 64 + lane) * 8));
            acc[nt] = __builtin_amdgcn_mfma_f32_16x16x32_bf16(a, b, acc[nt], 0, 0, 0);
        }
    }
#pragma unroll
    for (int kt = 0; kt < KT; ++kt) {
        bf16x8 a;
        if constexpr (DSTF) a = cvt8((const float*)Xdst_ + (size_t)(m0 + l15) * KF + kt * 32 + quad * 8);
        else                a = *reinterpret_cast<const bf16x8*>((const u16*)Xdst_ + (size_t)(m0 + l15) * KF + kt * 32 + quad * 8);
#pragma unroll
        for (int nt = 0; nt < 8; ++nt) {
            bf16x8 b = *reinterpret_cast<const bf16x8*>(Wrp + (size_t)(((kt * 8 + nt) * 64 + lane) * 8));
            acc[nt] = __builtin_amdgcn_mfma_f32_16x16x32_bf16(a, b, acc[nt], 0, 0, 0);
        }
    }
#pragma unroll
    for (int nt = 0; nt < 8; ++nt) {
        int col = nt * 16 + l15;
        float bv = bias[col];
#pragma unroll
        for (int r = 0; r < 4; ++r) {
            int row = m0 + quad * 4 + r;
            float v = fmaxf(acc[nt][r] + bv, 0.f);
            if constexpr (OUTF) ((float*)out_)[(size_t)row * 128 + col] = v;
            else                ((u16*)out_)[(size_t)row * 128 + col] = f2bf(v);
            if constexpr (SHADOW) out_bf[(size_t)row * 128 + col] = f2bf(v);
        }
    }
}

// ---------------- fused classifier + risk heads (X fp32) ----------------
__global__ void __launch_bounds__(256) head_fused(
    const float* __restrict__ X, const u16* __restrict__ W1p,
    const float* __restrict__ b1a, const float* __restrict__ b1b,
    const float* __restrict__ cW2, const float* __restrict__ cb2,
    const float* __restrict__ rW2, const float* __restrict__ rb2,
    float* __restrict__ pred, float* __restrict__ risk, int M)
{
    __shared__ alignas(16) u16 lds[4][16][128 + LDS_PAD];
    const int lane = threadIdx.x & 63;
    const int wv = threadIdx.x >> 6;
    const int m0 = (blockIdx.x * 4 + wv) * 16;
    const bool active = (m0 < M);
    const int quad = lane >> 4;
    const int l15 = lane & 15;

    if (active) {
        f32x4 acc[8];
#pragma unroll
        for (int i = 0; i < 8; ++i) acc[i] = (f32x4){0.f, 0.f, 0.f, 0.f};
#pragma unroll
        for (int kt = 0; kt < 4; ++kt) {
            bf16x8 a = cvt8(X + (size_t)(m0 + l15) * 128 + kt * 32 + quad * 8);
#pragma unroll
            for (int nt = 0; nt < 8; ++nt) {
                bf16x8 b = *reinterpret_cast<const bf16x8*>(W1p + (size_t)(((kt * 8 + nt) * 64 + lane) * 8));
                acc[nt] = __builtin_amdgcn_mfma_f32_16x16x32_bf16(a, b, acc[nt], 0, 0, 0);
            }
        }
#pragma unroll
        for (int nt = 0; nt < 8; ++nt) {
            int col = nt * 16 + l15;
            float bv = (col < 64) ? b1a[col] : b1b[col - 64];
#pragma unroll
            for (int r = 0; r < 4; ++r) {
                float v = fmaxf(acc[nt][r] + bv, 0.f);
                lds[wv][quad * 4 + r][col] = f2bf(v);
            }
        }
    }
    __syncthreads();
    if (!active) return;

    float w0 = cW2[lane * 2 + 0];
    float w1 = cW2[lane * 2 + 1];
    float w2 = rW2[lane];
    float cb0 = cb2[0], cb1v = cb2[1], rb = rb2[0];
    for (int r = 0; r < 16; ++r) {
        float t1 = bf2f(lds[wv][r][lane]);
        float t2 = bf2f(lds[wv][r][64 + lane]);
        float s0 = t1 * w0;
        float s1 = t1 * w1;
        float s2 = t2 * w2;
        for (int off = 32; off > 0; off >>= 1) {
            s0 += __shfl_xor(s0, off);
            s1 += __shfl_xor(s1, off);
            s2 += __shfl_xor(s2, off);
        }
        if (lane == 0) {
            int row = m0 + r;
            pred[(size_t)row * 2 + 0] = s0 + cb0;
            pred[(size_t)row * 2 + 1] = s1 + cb1v;
            float z = s2 + rb;
            risk[row] = 1.f / (1.f + __expf(-z));
        }
    }
}

// ---------------- host ----------------
#define OFF_CNT_M  ((size_t)0)
#define OFF_CNT_C  ((size_t)262144)
#define OFF_BKT_M  ((size_t)1  << 20)
#define OFF_BKT_C  ((size_t)14 << 20)
#define OFF_HM     ((size_t)27 << 20)
#define OFF_PACK   ((size_t)40 << 20)
#define OFF_XC     ((size_t)41 << 20)
#define OFF_XM     ((size_t)54 << 20)
#define OFF_HCB    ((size_t)61 << 20)
#define WS_SHADOW_NEED ((size_t)87 << 20)

extern "C" void kernel_launch(void* const* d_in, const int* in_sizes, int n_in,
                              void* d_out, int out_size, void* d_ws, size_t ws_size,
                              hipStream_t stream)
{
    const float* x_card   = (const float*)d_in[0];
    const float* x_merch  = (const float*)d_in[1];
    const int* src_cm     = (const int*)d_in[2];
    const int* dst_cm     = (const int*)d_in[3];
    const int* src_mc     = (const int*)d_in[4];
    const int* dst_mc     = (const int*)d_in[5];
    const float* Wl0_cm   = (const float*)d_in[6];
    const float* bl0_cm   = (const float*)d_in[7];
    const float* Wr0_cm   = (const float*)d_in[8];
    const float* Wl0_mc   = (const float*)d_in[9];
    const float* bl0_mc   = (const float*)d_in[10];
    const float* Wr0_mc   = (const float*)d_in[11];
    const float* Wl1_cm   = (const float*)d_in[12];
    const float* bl1_cm   = (const float*)d_in[13];
    const float* Wr1_cm   = (const float*)d_in[14];
    const float* Wl1_mc   = (const float*)d_in[15];
    const float* bl1_mc   = (const float*)d_in[16];
    const float* Wr1_mc   = (const float*)d_in[17];
    const float* cW1_card = (const float*)d_in[18];
    const float* cb1_card = (const float*)d_in[19];
    const float* cW2_card = (const float*)d_in[20];
    const float* cb2_card = (const float*)d_in[21];
    const float* cW1_mer  = (const float*)d_in[22];
    const float* cb1_mer  = (const float*)d_in[23];
    const float* cW2_mer  = (const float*)d_in[24];
    const float* cb2_mer  = (const float*)d_in[25];
    const float* rW1      = (const float*)d_in[26];
    const float* rb1      = (const float*)d_in[27];
    const float* rW2      = (const float*)d_in[28];
    const float* rb2      = (const float*)d_in[29];

    const int nCard  = in_sizes[0] / 64;   // 100000
    const int nMerch = in_sizes[1] / 64;   // 50000
    const int E      = in_sizes[2];        // 1000000

    char* ws = (char*)d_ws;
    int* cnt_m    = (int*)(ws + OFF_CNT_M);
    int* cnt_c    = (int*)(ws + OFF_CNT_C);
    u32* bucket_m = (u32*)(ws + OFF_BKT_M);
    u16* bucket_c = (u16*)(ws + OFF_BKT_C);
    u16* h_m      = (u16*)(ws + OFF_HM);
    u16* pw       = (u16*)(ws + OFF_PACK);
    u16* pWl0_cm = pw + 0 * 16384;
    u16* pWr0_cm = pw + 1 * 16384;
    u16* pWl0_mc = pw + 2 * 16384;
    u16* pWr0_mc = pw + 3 * 16384;
    u16* pWl1_cm = pw + 4 * 16384;
    u16* pWr1_cm = pw + 5 * 16384;
    u16* pWl1_mc = pw + 6 * 16384;
    u16* pWr1_mc = pw + 7 * 16384;
    u16* pHeadC  = pw + 8 * 16384;
    u16* pHeadM  = pw + 9 * 16384;
    u16* xc_bf   = (u16*)(ws + OFF_XC);
    u16* xm_bf   = (u16*)(ws + OFF_XM);
    u16* hc_bf   = (u16*)(ws + OFF_HCB);

    const bool shadow = (ws_size >= WS_SHADOW_NEED);

    float* out     = (float*)d_out;
    float* o_hc2   = out;
    float* o_hm2   = o_hc2 + (size_t)nCard * 128;
    float* o_predc = o_hm2 + (size_t)nMerch * 128;
    float* o_predm = o_predc + (size_t)nCard * 2;
    float* o_riskc = o_predm + (size_t)nMerch * 2;
    float* o_riskm = o_riskc + (size_t)nCard;

    // zero the two count arrays (required: build uses global atomicAdd)
    hipMemsetAsync(ws, 0, OFF_CNT_C + (size_t)nCard * sizeof(int), stream);

    PackArgs pa;
    pa.d[0]  = { Wl0_cm,   pWl0_cm,  64, 128, 0 };
    pa.d[1]  = { Wr0_cm,   pWr0_cm,  64, 128, 0 };
    pa.d[2]  = { Wl0_mc,   pWl0_mc,  64, 128, 0 };
    pa.d[3]  = { Wr0_mc,   pWr0_mc,  64, 128, 0 };
    pa.d[4]  = { Wl1_cm,   pWl1_cm, 128, 128, 0 };
    pa.d[5]  = { Wr1_cm,   pWr1_cm, 128, 128, 0 };
    pa.d[6]  = { Wl1_mc,   pWl1_mc, 128, 128, 0 };
    pa.d[7]  = { Wr1_mc,   pWr1_mc, 128, 128, 0 };
    pa.d[8]  = { cW1_card, pHeadC,  128,  64, 0 };
    pa.d[9]  = { rW1,      pHeadC,  128,  64, 4 };
    pa.d[10] = { cW1_mer,  pHeadM,  128,  64, 0 };
    pa.d[11] = { rW1,      pHeadM,  128,  64, 4 };
    pack_all<<<dim3(64, 12), 256, 0, stream>>>(pa);

    build_buckets_xcd<<<dim3(NXCD, ECHUNK, 2), 256, 0, stream>>>(
        src_cm, dst_cm, src_mc, dst_mc, cnt_m, bucket_m, cnt_c, bucket_c,
        E, nMerch, nCard);

    if (shadow) {
        f32_to_bf16<<<(nCard * 64 / 4 + 255) / 256, 256, 0, stream>>>(x_card, xc_bf, nCard * 64);
        f32_to_bf16<<<(nMerch * 64 / 4 + 255) / 256, 256, 0, stream>>>(x_merch, xm_bf, nMerch * 64);

        // ---- layer 0 (all gathers bf16) ----
        sage_fused<u32, 64, false, false, false, false><<<(nMerch + 63) / 64, 256, 0, stream>>>(
            xc_bf, bucket_m, cnt_m, pWl0_cm, xm_bf, pWr0_cm, bl0_cm, h_m, nullptr, nMerch);
        sage_fused<u16, 64, false, false, true, true><<<(nCard + 63) / 64, 256, 0, stream>>>(
            xm_bf, bucket_c, cnt_c, pWl0_mc, xc_bf, pWr0_mc, bl0_mc, o_hc2, hc_bf, nCard);

        // ---- layer 1 ----
        sage_fused<u32, 128, false, false, true, false><<<(nMerch + 63) / 64, 256, 0, stream>>>(
            hc_bf, bucket_m, cnt_m, pWl1_cm, h_m, pWr1_cm, bl1_cm, o_hm2, nullptr, nMerch);
        sage_fused<u16, 128, false, false, true, false><<<(nCard + 63) / 64, 256, 0, stream>>>(
            h_m, bucket_c, cnt_c, pWl1_mc, hc_bf, pWr1_mc, bl1_mc, o_hc2, nullptr, nCard);
    } else {
        // fallback: fp32 gathers, in-place h_c update (row-disjoint)
        sage_fused<u32, 64, true, true, false, false><<<(nMerch + 63) / 64, 256, 0, stream>>>(
            x_card, bucket_m, cnt_m, pWl0_cm, x_merch, pWr0_cm, bl0_cm, h_m, nullptr, nMerch);
        sage_fused<u16, 64, true, true, true, false><<<(nCard + 63) / 64, 256, 0, stream>>>(
            x_merch, bucket_c, cnt_c, pWl0_mc, x_card, pWr0_mc, bl0_mc, o_hc2, nullptr, nCard);
        sage_fused<u32, 128, true, false, true, false><<<(nMerch + 63) / 64, 256, 0, stream>>>(
            o_hc2, bucket_m, cnt_m, pWl1_cm, h_m, pWr1_cm, bl1_cm, o_hm2, nullptr, nMerch);
        sage_fused<u16, 128, false, true, true, false><<<(nCard + 63) / 64, 256, 0, stream>>>(
            h_m, bucket_c, cnt_c, pWl1_mc, o_hc2, pWr1_mc, bl1_mc, o_hc2, nullptr, nCard);
    }

    // ---- heads ----
    head_fused<<<(nCard + 63) / 64, 256, 0, stream>>>(
        o_hc2, pHeadC, cb1_card, rb1, cW2_card, cb2_card, rW2, rb2, o_predc, o_riskc, nCard);
    head_fused<<<(nMerch + 63) / 64, 256, 0, stream>>>(
        o_hm2, pHeadM, cb1_mer, rb1, cW2_mer, cb2_mer, rW2, rb2, o_predm, o_riskm, nMerch);
}

// Round 8
// 562.084 us; speedup vs baseline: 3.3786x; 1.0979x over previous
//
#include <hip/hip_runtime.h>

// HeteroGraphSAGE on MI355X — fp32 I/O, bf16 MFMA internals.
// R8: (1) prep kernel = build(XCD-part, nt loads) + pack + f32->bf16 converts
//     in ONE dispatch (independent work rides inside latency-bound build);
//     (2) sage pairs merged into single dispatches (overlap two latency-bound
//     kernels); heads merged too. 11 -> 5 dispatches.
//     (3) gather: 16 row-counts preloaded in one coalesced load + bucket-row
//     index prefetch pipelined one row ahead (kills 16 serial index stalls).
//
// ws layout (bytes):
//   cnt_m @0  cnt_c @256K  bucket_m @1MiB (u32)  bucket_c @14MiB (u16)
//   h_m @27MiB (bf16)  packed @40MiB (10*32KiB)
//   shadow (ws>=87MiB): xc_bf @41MiB  xm_bf @54MiB  hc_bf @61MiB

typedef unsigned short u16;
typedef unsigned int u32;
typedef short bf16x8 __attribute__((ext_vector_type(8)));
typedef float f32x4 __attribute__((ext_vector_type(4)));
typedef u16 u16x4 __attribute__((ext_vector_type(4)));
typedef u16 u16x8 __attribute__((ext_vector_type(8)));

#define CAP 64
#define LDS_PAD 8
#define NXCD 8
#define ECHUNK 64
#define NBUILD (NXCD * ECHUNK * 2)   // 1024
#define NPACK  768                   // 64 x 12

__device__ __forceinline__ float bf2f(u16 u) {
    union { u32 i; float f; } v; v.i = ((u32)u) << 16; return v.f;
}
__device__ __forceinline__ u16 f2bf(float f) {
    union { float f; u32 i; } v; v.f = f;
    u32 i = v.i;
    return (u16)((i + 0x7FFFu + ((i >> 16) & 1u)) >> 16);   // RNE
}
__device__ __forceinline__ bf16x8 cvt8(const float* p) {
    bf16x8 r;
#pragma unroll
    for (int i = 0; i < 8; ++i) r[i] = (short)f2bf(p[i]);
    return r;
}

// ---------------- prep: build + pack + converts in one dispatch ----------------
struct PackDesc { const float* src; u16* dst; int K; int Nsrc; int ntOff; };
struct PrepArgs {
    // build
    const int* src_cm; const int* dst_cm; const int* src_mc; const int* dst_mc;
    int* cnt_m; u32* bucket_m; int* cnt_c; u16* bucket_c;
    int E; int nMerch; int nCard;
    // converts (shadow only; ncBlk/nmBlk = 0 to skip)
    const float* xc; u16* xcb; int ncBlk;
    const float* xm; u16* xmb; int nmBlk;
    // pack
    PackDesc pd[12];
};

__global__ void __launch_bounds__(256) prep(PrepArgs a) {
    const int b = blockIdx.x;
    if (b < NBUILD) {
        // ---- bucket build (XCD-partitioned, nontemporal edge streams) ----
        const int g = b & 7;
        const int chunk = (b >> 3) & 63;
        const bool dirA = b < (NBUILD / 2);
        const int nNode = dirA ? a.nMerch : a.nCard;
        const int lo = (int)((long long)g * nNode / NXCD);
        const int hi = (int)((long long)(g + 1) * nNode / NXCD);
        const int* dst = dirA ? a.dst_cm : a.dst_mc;
        const int* src = dirA ? a.src_cm : a.src_mc;
        int* cnt = dirA ? a.cnt_m : a.cnt_c;
        const int e0 = (int)((long long)chunk * a.E / ECHUNK);
        const int e1 = (int)((long long)(chunk + 1) * a.E / ECHUNK);
        for (int i = e0 + threadIdx.x; i < e1; i += 256) {
            int d = __builtin_nontemporal_load(dst + i);
            if (d >= lo && d < hi) {
                int slot = atomicAdd(&cnt[d], 1);
                if (slot < CAP) {
                    int s = __builtin_nontemporal_load(src + i);
                    if (dirA) a.bucket_m[(size_t)d * CAP + slot] = (u32)s;
                    else      a.bucket_c[(size_t)d * CAP + slot] = (u16)s;
                }
            }
        }
    } else if (b < NBUILD + NPACK) {
        // ---- weight packing: fp32 W[K,Nsrc] -> bf16 MFMA B fragments ----
        int e = b - NBUILD;
        PackDesc pd = a.pd[e >> 6];
        int idx = (e & 63) * 256 + threadIdx.x;
        int j = idx & 7;
        int lane = (idx >> 3) & 63;
        int t = idx >> 9;
        int nLocal = pd.Nsrc >> 4;
        int ntl = t % nLocal;
        int kt = t / nLocal;
        if (kt >= (pd.K >> 5)) return;
        int k = kt * 32 + ((lane >> 4) << 3) + j;
        int n = ntl * 16 + (lane & 15);
        pd.dst[(((kt * 8 + pd.ntOff + ntl) * 64) + lane) * 8 + j] = f2bf(pd.src[k * pd.Nsrc + n]);
    } else {
        // ---- fp32 -> bf16 shadow converts ----
        int e = b - NBUILD - NPACK;
        const float* s;
        u16* d;
        int n;
        if (e < a.ncBlk) { s = a.xc; d = a.xcb; n = a.nCard * 64; }
        else             { e -= a.ncBlk; s = a.xm; d = a.xmb; n = a.nMerch * 64; }
        int i = (e * 256 + threadIdx.x) * 4;
        if (i >= n) return;
        f32x4 v = *reinterpret_cast<const f32x4*>(s + i);
        u16x4 o;
#pragma unroll
        for (int j = 0; j < 4; ++j) o[j] = f2bf(v[j]);
        *reinterpret_cast<u16x4*>(d + i) = o;
    }
}

// ---------------- paired fused SAGE layer (shadow path: all bf16 sources) ----------------
// out = relu(mean_nbr(src) @ Wl + dst @ Wr + bias), N=128.
struct SageJob {
    const u16* src;      // bf16 gather source [*, KF]
    const void* adj;     // bucket rows, CAP wide (u32 if idx32 else u16)
    const int* cnt;
    const u16* Wlp;      // packed Wl fragments
    const u16* dst;      // bf16 lin_r source [M, KF]
    const u16* Wrp;
    const float* bias;   // [128]
    float* outF;         // fp32 out [M,128] or null
    u16* outH;           // bf16 out or null
    u16* outS;           // bf16 shadow out or null
    int M;
    int idx32;
    int nBlk;
};

template<int KF>
__global__ void __launch_bounds__(256) sage_pair(SageJob j0, SageJob j1) {
    constexpr int NV = KF / 16;
    __shared__ alignas(16) u16 lds[4][16][128 + LDS_PAD];
    const bool second = (int)blockIdx.x >= j0.nBlk;
    const SageJob& j = second ? j1 : j0;
    const int bx = second ? blockIdx.x - j0.nBlk : blockIdx.x;
    const int lane = threadIdx.x & 63;
    const int wv = threadIdx.x >> 6;
    const int m0 = (bx * 4 + wv) * 16;
    const bool active = (m0 < j.M);     // M % 16 == 0 -> all 16 rows valid
    const int quad = lane >> 4;
    const int l15 = lane & 15;

    if (active) {
        const u16* srcH = j.src;
        const u32* adj32 = (const u32*)j.adj;
        const u16* adj16 = (const u16*)j.adj;
        const bool i32 = (j.idx32 != 0);
        // one coalesced load covers all 16 row counts
        int cv = j.cnt[m0 + l15];
        // prefetch row 0 bucket indices
        int cc_n = min(__shfl(cv, 0), CAP);
        int sidx_n = 0;
        if (lane < cc_n)
            sidx_n = i32 ? (int)adj32[(size_t)m0 * CAP + lane]
                         : (int)adj16[(size_t)m0 * CAP + lane];
        for (int r = 0; r < 16; ++r) {
            const int node = m0 + r;
            const int cc = cc_n;
            const int cfull = __shfl(cv, r);
            const int sidx = sidx_n;
            if (r < 15) {   // pipeline next row's index load behind this row's gathers
                cc_n = min(__shfl(cv, r + 1), CAP);
                sidx_n = 0;
                if (lane < cc_n)
                    sidx_n = i32 ? (int)adj32[(size_t)(node + 1) * CAP + lane]
                                 : (int)adj16[(size_t)(node + 1) * CAP + lane];
            }
            float inv = 1.f / (float)max(cfull, 1);
            float acc0[NV], acc1[NV];
#pragma unroll
            for (int i = 0; i < NV; ++i) { acc0[i] = 0.f; acc1[i] = 0.f; }
            for (int t = 0; t < cc; t += 8) {
                int k0 = t + quad;
                int k1 = t + quad + 4;
                int s0 = __shfl(sidx, k0);
                int s1 = __shfl(sidx, k1);
                bool p0 = k0 < cc;
                bool p1 = k1 < cc;
                if constexpr (NV == 8) {
                    bf16x8 u0 = *(const bf16x8*)(srcH + (size_t)s0 * KF + l15 * 8);
                    bf16x8 u1 = *(const bf16x8*)(srcH + (size_t)s1 * KF + l15 * 8);
#pragma unroll
                    for (int i = 0; i < 8; ++i) {
                        acc0[i] += p0 ? bf2f((u16)u0[i]) : 0.f;
                        acc1[i] += p1 ? bf2f((u16)u1[i]) : 0.f;
                    }
                } else {
                    u16x4 u0 = *(const u16x4*)(srcH + (size_t)s0 * KF + l15 * 4);
                    u16x4 u1 = *(const u16x4*)(srcH + (size_t)s1 * KF + l15 * 4);
#pragma unroll
                    for (int i = 0; i < 4; ++i) {
                        acc0[i] += p0 ? bf2f(u0[i]) : 0.f;
                        acc1[i] += p1 ? bf2f(u1[i]) : 0.f;
                    }
                }
            }
            u16 packed[NV];
#pragma unroll
            for (int i = 0; i < NV; ++i) {
                float m = acc0[i] + acc1[i];
                m += __shfl_xor(m, 16);
                m += __shfl_xor(m, 32);
                packed[i] = f2bf(m * inv);
            }
            if (quad == 0) {
                if constexpr (NV == 8) *(u16x8*)&lds[wv][r][l15 * 8] = *(const u16x8*)packed;
                else                   *(u16x4*)&lds[wv][r][l15 * 4] = *(const u16x4*)packed;
            }
        }
    }
    __syncthreads();
    if (!active) return;

    constexpr int KT = KF >> 5;
    f32x4 acc[8];
#pragma unroll
    for (int i = 0; i < 8; ++i) acc[i] = (f32x4){0.f, 0.f, 0.f, 0.f};

#pragma unroll
    for (int kt = 0; kt < KT; ++kt) {
        bf16x8 a = *reinterpret_cast<const bf16x8*>(&lds[wv][l15][kt * 32 + quad * 8]);
#pragma unroll
        for (int nt = 0; nt < 8; ++nt) {
            bf16x8 bfr = *reinterpret_cast<const bf16x8*>(j.Wlp + (size_t)(((kt * 8 + nt) * 64 + lane) * 8));
            acc[nt] = __builtin_amdgcn_mfma_f32_16x16x32_bf16(a, bfr, acc[nt], 0, 0, 0);
        }
    }
#pragma unroll
    for (int kt = 0; kt < KT; ++kt) {
        bf16x8 a = *reinterpret_cast<const bf16x8*>(j.dst + (size_t)(m0 + l15) * KF + kt * 32 + quad * 8);
#pragma unroll
        for (int nt = 0; nt < 8; ++nt) {
            bf16x8 bfr = *reinterpret_cast<const bf16x8*>(j.Wrp + (size_t)(((kt * 8 + nt) * 64 + lane) * 8));
            acc[nt] = __builtin_amdgcn_mfma_f32_16x16x32_bf16(a, bfr, acc[nt], 0, 0, 0);
        }
    }
#pragma unroll
    for (int nt = 0; nt < 8; ++nt) {
        int col = nt * 16 + l15;
        float bv = j.bias[col];
#pragma unroll
        for (int r = 0; r < 4; ++r) {
            int row = m0 + quad * 4 + r;
            float v = fmaxf(acc[nt][r] + bv, 0.f);
            if (j.outF) j.outF[(size_t)row * 128 + col] = v;
            if (j.outH) j.outH[(size_t)row * 128 + col] = f2bf(v);
            if (j.outS) j.outS[(size_t)row * 128 + col] = f2bf(v);
        }
    }
}

// ---------------- fallback SAGE (fp32 sources, no shadow ws) ----------------
template<typename IdxT, int KF, bool SRCF, bool DSTF, bool OUTF>
__global__ void __launch_bounds__(256) sage_fused(
    const void* __restrict__ Xsrc_, const IdxT* __restrict__ adj,
    const int* __restrict__ cnt,
    const u16* __restrict__ Wlp, const void* __restrict__ Xdst_,
    const u16* __restrict__ Wrp, const float* __restrict__ bias,
    void* __restrict__ out_, int M)
{
    constexpr int NV = KF / 16;
    __shared__ alignas(16) u16 lds[4][16][128 + LDS_PAD];
    const int lane = threadIdx.x & 63;
    const int wv = threadIdx.x >> 6;
    const int m0 = (blockIdx.x * 4 + wv) * 16;
    const bool active = (m0 < M);
    const int quad = lane >> 4;
    const int l15 = lane & 15;

    if (active) {
        const float* srcF = (const float*)Xsrc_;
        const u16*   srcH = (const u16*)Xsrc_;
        for (int r = 0; r < 16; ++r) {
            int node = m0 + r;
            int c = cnt[node];
            int cc = min(c, CAP);
            int sidx = (lane < cc) ? (int)adj[(size_t)node * CAP + lane] : 0;
            float inv = 1.f / (float)max(c, 1);
            float acc0[NV], acc1[NV];
#pragma unroll
            for (int i = 0; i < NV; ++i) { acc0[i] = 0.f; acc1[i] = 0.f; }
            for (int t = 0; t < cc; t += 8) {
                int k0 = t + quad, k1 = t + quad + 4;
                int s0 = __shfl(sidx, k0), s1 = __shfl(sidx, k1);
                bool p0 = k0 < cc, p1 = k1 < cc;
                if constexpr (SRCF) {
                    const f32x4* q0 = (const f32x4*)(srcF + (size_t)s0 * KF + l15 * NV);
                    const f32x4* q1 = (const f32x4*)(srcF + (size_t)s1 * KF + l15 * NV);
                    f32x4 u0 = q0[0], u1 = q1[0];
                    if constexpr (NV == 8) {
                        f32x4 w0 = q0[1], w1 = q1[1];
#pragma unroll
                        for (int i = 0; i < 4; ++i) {
                            acc0[4 + i] += p0 ? w0[i] : 0.f;
                            acc1[4 + i] += p1 ? w1[i] : 0.f;
                        }
                    }
#pragma unroll
                    for (int i = 0; i < 4; ++i) {
                        acc0[i] += p0 ? u0[i] : 0.f;
                        acc1[i] += p1 ? u1[i] : 0.f;
                    }
                } else {
                    if constexpr (NV == 8) {
                        bf16x8 u0 = *(const bf16x8*)(srcH + (size_t)s0 * KF + l15 * 8);
                        bf16x8 u1 = *(const bf16x8*)(srcH + (size_t)s1 * KF + l15 * 8);
#pragma unroll
                        for (int i = 0; i < 8; ++i) {
                            acc0[i] += p0 ? bf2f((u16)u0[i]) : 0.f;
                            acc1[i] += p1 ? bf2f((u16)u1[i]) : 0.f;
                        }
                    } else {
                        u16x4 u0 = *(const u16x4*)(srcH + (size_t)s0 * KF + l15 * 4);
                        u16x4 u1 = *(const u16x4*)(srcH + (size_t)s1 * KF + l15 * 4);
#pragma unroll
                        for (int i = 0; i < 4; ++i) {
                            acc0[i] += p0 ? bf2f(u0[i]) : 0.f;
                            acc1[i] += p1 ? bf2f(u1[i]) : 0.f;
                        }
                    }
                }
            }
            u16 packed[NV];
#pragma unroll
            for (int i = 0; i < NV; ++i) {
                float m = acc0[i] + acc1[i];
                m += __shfl_xor(m, 16);
                m += __shfl_xor(m, 32);
                packed[i] = f2bf(m * inv);
            }
            if (quad == 0) {
                if constexpr (NV == 8) *(u16x8*)&lds[wv][r][l15 * 8] = *(const u16x8*)packed;
                else                   *(u16x4*)&lds[wv][r][l15 * 4] = *(const u16x4*)packed;
            }
        }
    }
    __syncthreads();
    if (!active) return;

    constexpr int KT = KF >> 5;
    f32x4 acc[8];
#pragma unroll
    for (int i = 0; i < 8; ++i) acc[i] = (f32x4){0.f, 0.f, 0.f, 0.f};
#pragma unroll
    for (int kt = 0; kt < KT; ++kt) {
        bf16x8 a = *reinterpret_cast<const bf16x8*>(&lds[wv][l15][kt * 32 + quad * 8]);
#pragma unroll
        for (int nt = 0; nt < 8; ++nt) {
            bf16x8 b = *reinterpret_cast<const bf16x8*>(Wlp + (size_t)(((kt * 8 + nt) * 64 + lane) * 8));
            acc[nt] = __builtin_amdgcn_mfma_f32_16x16x32_bf16(a, b, acc[nt], 0, 0, 0);
        }
    }
#pragma unroll
    for (int kt = 0; kt < KT; ++kt) {
        bf16x8 a;
        if constexpr (DSTF) a = cvt8((const float*)Xdst_ + (size_t)(m0 + l15) * KF + kt * 32 + quad * 8);
        else                a = *reinterpret_cast<const bf16x8*>((const u16*)Xdst_ + (size_t)(m0 + l15) * KF + kt * 32 + quad * 8);
#pragma unroll
        for (int nt = 0; nt < 8; ++nt) {
            bf16x8 b = *reinterpret_cast<const bf16x8*>(Wrp + (size_t)(((kt * 8 + nt) * 64 + lane) * 8));
            acc[nt] = __builtin_amdgcn_mfma_f32_16x16x32_bf16(a, b, acc[nt], 0, 0, 0);
        }
    }
#pragma unroll
    for (int nt = 0; nt < 8; ++nt) {
        int col = nt * 16 + l15;
        float bv = bias[col];
#pragma unroll
        for (int r = 0; r < 4; ++r) {
            int row = m0 + quad * 4 + r;
            float v = fmaxf(acc[nt][r] + bv, 0.f);
            if constexpr (OUTF) ((float*)out_)[(size_t)row * 128 + col] = v;
            else                ((u16*)out_)[(size_t)row * 128 + col] = f2bf(v);
        }
    }
}

// ---------------- paired classifier + risk heads ----------------
struct HeadJob {
    const float* X; const u16* W1p;
    const float* b1a; const float* b1b;
    const float* cW2; const float* cb2;
    const float* rW2; const float* rb2;
    float* pred; float* risk; int M; int nBlk;
};

__global__ void __launch_bounds__(256) head_pair(HeadJob h0, HeadJob h1) {
    __shared__ alignas(16) u16 lds[4][16][128 + LDS_PAD];
    const bool second = (int)blockIdx.x >= h0.nBlk;
    const HeadJob& h = second ? h1 : h0;
    const int bx = second ? blockIdx.x - h0.nBlk : blockIdx.x;
    const int lane = threadIdx.x & 63;
    const int wv = threadIdx.x >> 6;
    const int m0 = (bx * 4 + wv) * 16;
    const bool active = (m0 < h.M);
    const int quad = lane >> 4;
    const int l15 = lane & 15;

    if (active) {
        f32x4 acc[8];
#pragma unroll
        for (int i = 0; i < 8; ++i) acc[i] = (f32x4){0.f, 0.f, 0.f, 0.f};
#pragma unroll
        for (int kt = 0; kt < 4; ++kt) {
            bf16x8 a = cvt8(h.X + (size_t)(m0 + l15) * 128 + kt * 32 + quad * 8);
#pragma unroll
            for (int nt = 0; nt < 8; ++nt) {
                bf16x8 b = *reinterpret_cast<const bf16x8*>(h.W1p + (size_t)(((kt * 8 + nt) * 64 + lane) * 8));
                acc[nt] = __builtin_amdgcn_mfma_f32_16x16x32_bf16(a, b, acc[nt], 0, 0, 0);
            }
        }
#pragma unroll
        for (int nt = 0; nt < 8; ++nt) {
            int col = nt * 16 + l15;
            float bv = (col < 64) ? h.b1a[col] : h.b1b[col - 64];
#pragma unroll
            for (int r = 0; r < 4; ++r) {
                float v = fmaxf(acc[nt][r] + bv, 0.f);
                lds[wv][quad * 4 + r][col] = f2bf(v);
            }
        }
    }
    __syncthreads();
    if (!active) return;

    float w0 = h.cW2[lane * 2 + 0];
    float w1 = h.cW2[lane * 2 + 1];
    float w2 = h.rW2[lane];
    float cb0 = h.cb2[0], cb1v = h.cb2[1], rb = h.rb2[0];
    for (int r = 0; r < 16; ++r) {
        float t1 = bf2f(lds[wv][r][lane]);
        float t2 = bf2f(lds[wv][r][64 + lane]);
        float s0 = t1 * w0;
        float s1 = t1 * w1;
        float s2 = t2 * w2;
        for (int off = 32; off > 0; off >>= 1) {
            s0 += __shfl_xor(s0, off);
            s1 += __shfl_xor(s1, off);
            s2 += __shfl_xor(s2, off);
        }
        if (lane == 0) {
            int row = m0 + r;
            h.pred[(size_t)row * 2 + 0] = s0 + cb0;
            h.pred[(size_t)row * 2 + 1] = s1 + cb1v;
            float z = s2 + rb;
            h.risk[row] = 1.f / (1.f + __expf(-z));
        }
    }
}

// ---------------- host ----------------
#define OFF_CNT_M  ((size_t)0)
#define OFF_CNT_C  ((size_t)262144)
#define OFF_BKT_M  ((size_t)1  << 20)
#define OFF_BKT_C  ((size_t)14 << 20)
#define OFF_HM     ((size_t)27 << 20)
#define OFF_PACK   ((size_t)40 << 20)
#define OFF_XC     ((size_t)41 << 20)
#define OFF_XM     ((size_t)54 << 20)
#define OFF_HCB    ((size_t)61 << 20)
#define WS_SHADOW_NEED ((size_t)87 << 20)

extern "C" void kernel_launch(void* const* d_in, const int* in_sizes, int n_in,
                              void* d_out, int out_size, void* d_ws, size_t ws_size,
                              hipStream_t stream)
{
    const float* x_card   = (const float*)d_in[0];
    const float* x_merch  = (const float*)d_in[1];
    const int* src_cm     = (const int*)d_in[2];
    const int* dst_cm     = (const int*)d_in[3];
    const int* src_mc     = (const int*)d_in[4];
    const int* dst_mc     = (const int*)d_in[5];
    const float* Wl0_cm   = (const float*)d_in[6];
    const float* bl0_cm   = (const float*)d_in[7];
    const float* Wr0_cm   = (const float*)d_in[8];
    const float* Wl0_mc   = (const float*)d_in[9];
    const float* bl0_mc   = (const float*)d_in[10];
    const float* Wr0_mc   = (const float*)d_in[11];
    const float* Wl1_cm   = (const float*)d_in[12];
    const float* bl1_cm   = (const float*)d_in[13];
    const float* Wr1_cm   = (const float*)d_in[14];
    const float* Wl1_mc   = (const float*)d_in[15];
    const float* bl1_mc   = (const float*)d_in[16];
    const float* Wr1_mc   = (const float*)d_in[17];
    const float* cW1_card = (const float*)d_in[18];
    const float* cb1_card = (const float*)d_in[19];
    const float* cW2_card = (const float*)d_in[20];
    const float* cb2_card = (const float*)d_in[21];
    const float* cW1_mer  = (const float*)d_in[22];
    const float* cb1_mer  = (const float*)d_in[23];
    const float* cW2_mer  = (const float*)d_in[24];
    const float* cb2_mer  = (const float*)d_in[25];
    const float* rW1      = (const float*)d_in[26];
    const float* rb1      = (const float*)d_in[27];
    const float* rW2      = (const float*)d_in[28];
    const float* rb2      = (const float*)d_in[29];

    const int nCard  = in_sizes[0] / 64;   // 100000
    const int nMerch = in_sizes[1] / 64;   // 50000
    const int E      = in_sizes[2];        // 1000000

    char* ws = (char*)d_ws;
    int* cnt_m    = (int*)(ws + OFF_CNT_M);
    int* cnt_c    = (int*)(ws + OFF_CNT_C);
    u32* bucket_m = (u32*)(ws + OFF_BKT_M);
    u16* bucket_c = (u16*)(ws + OFF_BKT_C);
    u16* h_m      = (u16*)(ws + OFF_HM);
    u16* pw       = (u16*)(ws + OFF_PACK);
    u16* pWl0_cm = pw + 0 * 16384;
    u16* pWr0_cm = pw + 1 * 16384;
    u16* pWl0_mc = pw + 2 * 16384;
    u16* pWr0_mc = pw + 3 * 16384;
    u16* pWl1_cm = pw + 4 * 16384;
    u16* pWr1_cm = pw + 5 * 16384;
    u16* pWl1_mc = pw + 6 * 16384;
    u16* pWr1_mc = pw + 7 * 16384;
    u16* pHeadC  = pw + 8 * 16384;
    u16* pHeadM  = pw + 9 * 16384;
    u16* xc_bf   = (u16*)(ws + OFF_XC);
    u16* xm_bf   = (u16*)(ws + OFF_XM);
    u16* hc_bf   = (u16*)(ws + OFF_HCB);

    const bool shadow = (ws_size >= WS_SHADOW_NEED);

    float* out     = (float*)d_out;
    float* o_hc2   = out;
    float* o_hm2   = o_hc2 + (size_t)nCard * 128;
    float* o_predc = o_hm2 + (size_t)nMerch * 128;
    float* o_predm = o_predc + (size_t)nCard * 2;
    float* o_riskc = o_predm + (size_t)nMerch * 2;
    float* o_riskm = o_riskc + (size_t)nCard;

    // zero the count arrays (build uses global atomicAdd)
    hipMemsetAsync(ws, 0, OFF_CNT_C + (size_t)nCard * sizeof(int), stream);

    // ---- prep: build + pack (+ converts when shadow) ----
    PrepArgs pa;
    pa.src_cm = src_cm; pa.dst_cm = dst_cm; pa.src_mc = src_mc; pa.dst_mc = dst_mc;
    pa.cnt_m = cnt_m; pa.bucket_m = bucket_m; pa.cnt_c = cnt_c; pa.bucket_c = bucket_c;
    pa.E = E; pa.nMerch = nMerch; pa.nCard = nCard;
    pa.xc = x_card;  pa.xcb = xc_bf; pa.ncBlk = shadow ? (nCard * 64 / 1024) : 0;   // 6250
    pa.xm = x_merch; pa.xmb = xm_bf; pa.nmBlk = shadow ? (nMerch * 64 / 1024) : 0;  // 3125
    pa.pd[0]  = { Wl0_cm,   pWl0_cm,  64, 128, 0 };
    pa.pd[1]  = { Wr0_cm,   pWr0_cm,  64, 128, 0 };
    pa.pd[2]  = { Wl0_mc,   pWl0_mc,  64, 128, 0 };
    pa.pd[3]  = { Wr0_mc,   pWr0_mc,  64, 128, 0 };
    pa.pd[4]  = { Wl1_cm,   pWl1_cm, 128, 128, 0 };
    pa.pd[5]  = { Wr1_cm,   pWr1_cm, 128, 128, 0 };
    pa.pd[6]  = { Wl1_mc,   pWl1_mc, 128, 128, 0 };
    pa.pd[7]  = { Wr1_mc,   pWr1_mc, 128, 128, 0 };
    pa.pd[8]  = { cW1_card, pHeadC,  128,  64, 0 };
    pa.pd[9]  = { rW1,      pHeadC,  128,  64, 4 };
    pa.pd[10] = { cW1_mer,  pHeadM,  128,  64, 0 };
    pa.pd[11] = { rW1,      pHeadM,  128,  64, 4 };
    int prepGrid = NBUILD + NPACK + pa.ncBlk + pa.nmBlk;
    prep<<<prepGrid, 256, 0, stream>>>(pa);

    const int nbM = (nMerch + 63) / 64;   // 782
    const int nbC = (nCard + 63) / 64;    // 1563

    if (shadow) {
        // ---- layer 0 pair ----
        SageJob a0 = { xc_bf, bucket_m, cnt_m, pWl0_cm, xm_bf, pWr0_cm, bl0_cm,
                       nullptr, h_m, nullptr, nMerch, 1, nbM };
        SageJob a1 = { xm_bf, bucket_c, cnt_c, pWl0_mc, xc_bf, pWr0_mc, bl0_mc,
                       o_hc2, nullptr, hc_bf, nCard, 0, nbC };
        sage_pair<64><<<nbM + nbC, 256, 0, stream>>>(a0, a1);

        // ---- layer 1 pair ----
        SageJob b0 = { hc_bf, bucket_m, cnt_m, pWl1_cm, h_m, pWr1_cm, bl1_cm,
                       o_hm2, nullptr, nullptr, nMerch, 1, nbM };
        SageJob b1 = { h_m, bucket_c, cnt_c, pWl1_mc, hc_bf, pWr1_mc, bl1_mc,
                       o_hc2, nullptr, nullptr, nCard, 0, nbC };
        sage_pair<128><<<nbM + nbC, 256, 0, stream>>>(b0, b1);
    } else {
        // fallback: fp32 gathers, in-place h_c update (row-disjoint)
        sage_fused<u32, 64, true, true, false><<<nbM, 256, 0, stream>>>(
            x_card, bucket_m, cnt_m, pWl0_cm, x_merch, pWr0_cm, bl0_cm, h_m, nMerch);
        sage_fused<u16, 64, true, true, true><<<nbC, 256, 0, stream>>>(
            x_merch, bucket_c, cnt_c, pWl0_mc, x_card, pWr0_mc, bl0_mc, o_hc2, nCard);
        sage_fused<u32, 128, true, false, true><<<nbM, 256, 0, stream>>>(
            o_hc2, bucket_m, cnt_m, pWl1_cm, h_m, pWr1_cm, bl1_cm, o_hm2, nMerch);
        sage_fused<u16, 128, false, true, true><<<nbC, 256, 0, stream>>>(
            h_m, bucket_c, cnt_c, pWl1_mc, o_hc2, pWr1_mc, bl1_mc, o_hc2, nCard);
    }

    // ---- heads pair ----
    HeadJob hc = { o_hc2, pHeadC, cb1_card, rb1, cW2_card, cb2_card, rW2, rb2,
                   o_predc, o_riskc, nCard, nbC };
    HeadJob hm = { o_hm2, pHeadM, cb1_mer, rb1, cW2_mer, cb2_mer, rW2, rb2,
                   o_predm, o_riskm, nMerch, nbM };
    head_pair<<<nbC + nbM, 256, 0, stream>>>(hc, hm);
}